// Round 14
// baseline (546.853 us; speedup 1.0000x reference)
//
#include <hip/hip_runtime.h>
#include <hip/hip_bf16.h>
#include <math.h>

#define B_ 8
#define C_ 128
#define H_ 64
#define W_ 64
#define HW_ 4096
#define HEADS_ 8
#define CH_ 16
#define HID_ 512

typedef unsigned short ushort_t;
struct __attribute__((aligned(8))) us4 { ushort_t x, y, z, w; };

typedef __attribute__((ext_vector_type(8))) short bf16x8;
typedef __attribute__((ext_vector_type(4))) float f32x4;

__device__ __forceinline__ float bf2f(ushort_t u) {
  return __uint_as_float(((unsigned int)u) << 16);
}
__device__ __forceinline__ ushort_t f2bu(float f) {
  __hip_bfloat16 h = __float2bfloat16(f);
  return *reinterpret_cast<ushort_t*>(&h);
}
__device__ __forceinline__ float toF(float v) { return v; }
__device__ __forceinline__ float toF(__hip_bfloat16 v) { return __bfloat162float(v); }
__device__ __forceinline__ void storeF(float* p, float v) { *p = v; }
__device__ __forceinline__ void storeF(__hip_bfloat16* p, float v) { *p = __float2bfloat16(v); }

// tanh-GELU: max dev from exact erf-GELU ~1e-3, straight-line
__device__ __forceinline__ float gelu_t(float x) {
  float z = 0.7978845608f * fmaf(0.044715f * x, x * x, x);
  float e = __expf(2.f * z);
  float th = 1.f - 2.f / (e + 1.f);
  return 0.5f * x * (1.f + th);
}

// ---------------- LayerNorm over channel dim ----------------
__global__ __launch_bounds__(256) void ln_ch(const float* __restrict__ x,
                                             const float* __restrict__ w,
                                             const float* __restrict__ b,
                                             float* __restrict__ out) {
  int p = blockIdx.x * 256 + threadIdx.x;  // over B*HW
  int bi = p >> 12;
  int pos = p & (HW_ - 1);
  const float* xb = x + (size_t)bi * C_ * HW_ + pos;
  float s = 0.f, ss = 0.f;
  for (int c = 0; c < C_; c++) {
    float v = xb[(size_t)c * HW_];
    s += v;
    ss = fmaf(v, v, ss);
  }
  float mu = s * (1.f / C_);
  float var = ss * (1.f / C_) - mu * mu;
  float inv = rsqrtf(var + 1e-5f);
  float* ob = out + (size_t)bi * C_ * HW_ + pos;
  for (int c = 0; c < C_; c++) {
    ob[(size_t)c * HW_] = (xb[(size_t)c * HW_] - mu) * inv * w[c] + b[c];
  }
}

// ---------------- weight prep: fp32 -> bf16, all six matrices ----------------
__global__ __launch_bounds__(256) void cvt_w(const float* __restrict__ wq,
                                             const float* __restrict__ wk,
                                             const float* __restrict__ wv,
                                             const float* __restrict__ apo,
                                             const float* __restrict__ fin,
                                             const float* __restrict__ fpo,
                                             ushort_t* __restrict__ dst) {
  int id = blockIdx.x * 256 + threadIdx.x;
  const float* src;
  int off;
  if (id < 16384) { src = wq; off = id; }
  else if (id < 32768) { src = wk; off = id - 16384; }
  else if (id < 49152) { src = wv; off = id - 32768; }
  else if (id < 98304) { src = apo; off = id - 49152; }
  else if (id < 229376) { src = fin; off = id - 98304; }
  else if (id < 425984) { src = fpo; off = id - 229376; }
  else return;
  dst[id] = f2bu(src[off]);
}

// ---------------- vector load/store helpers ----------------
__device__ __forceinline__ void load4f(const float* p, float* v) {
  float4 t = *(const float4*)p;
  v[0] = t.x; v[1] = t.y; v[2] = t.z; v[3] = t.w;
}
__device__ __forceinline__ void load4f(const __hip_bfloat16* p, float* v) {
  us4 t = *(const us4*)p;
  v[0] = bf2f(t.x); v[1] = bf2f(t.y); v[2] = bf2f(t.z); v[3] = bf2f(t.w);
}
__device__ __forceinline__ void store4f(float* p, const float* v) {
  float4 t; t.x = v[0]; t.y = v[1]; t.z = v[2]; t.w = v[3];
  *(float4*)p = t;
}
__device__ __forceinline__ void store4f(__hip_bfloat16* p, const float* v) {
  us4 t; t.x = f2bu(v[0]); t.y = f2bu(v[1]); t.z = f2bu(v[2]); t.w = f2bu(v[3]);
  *(us4*)p = t;
}

// load 16-elem window rv[j] = row[cb-4+j], zero-padded outside [0,64)
__device__ __forceinline__ void loadrow_bf(const __hip_bfloat16* __restrict__ rowp,
                                           int cb, float* rv) {
#pragma unroll
  for (int b = 0; b < 4; b++) {
    int co = cb - 4 + b * 4;
    if ((unsigned)co <= 60u) {
      us4 t = *(const us4*)(rowp + co);
      rv[b * 4 + 0] = bf2f(t.x); rv[b * 4 + 1] = bf2f(t.y);
      rv[b * 4 + 2] = bf2f(t.z); rv[b * 4 + 3] = bf2f(t.w);
    } else {
      rv[b * 4 + 0] = 0.f; rv[b * 4 + 1] = 0.f;
      rv[b * 4 + 2] = 0.f; rv[b * 4 + 3] = 0.f;
    }
  }
}
__device__ __forceinline__ void loadrow_f(const float* __restrict__ rowp,
                                          int cb, float* rv) {
#pragma unroll
  for (int b = 0; b < 4; b++) {
    int co = cb - 4 + b * 4;
    if ((unsigned)co <= 60u) {
      float4 t = *(const float4*)(rowp + co);
      rv[b * 4 + 0] = t.x; rv[b * 4 + 1] = t.y;
      rv[b * 4 + 2] = t.z; rv[b * 4 + 3] = t.w;
    } else {
      rv[b * 4 + 0] = 0.f; rv[b * 4 + 1] = 0.f;
      rv[b * 4 + 2] = 0.f; rv[b * 4 + 3] = 0.f;
    }
  }
}

// ------- conv1x1 as bf16 MFMA GEMM: Out[cout][HW] = W[cout][cin] @ In[cin][HW] -------
// LDS holds the input tile TRANSPOSED ([n][k], n-major, row stride ST2=136 bf16):
// a lane's B-fragment (8 contiguous k at fixed n) is ONE ds_read_b128 instead of
// 8 scalar ds_read_u16 (R13 analysis: scalar reads were 9:1 over MFMA cycles).
// Bank check: read bank-start = 4*(n+lk) mod 32 -> 8 lanes per 4-bank group =
// exactly the 1KB/wave LDS minimum (uniform). Staging: per-thread 4 scalar
// global loads (wave-coalesced along n) packed into one ds_write_b64.
template <typename Tin, typename Tout>
__global__ __launch_bounds__(256) void conv1x1_m(const Tin* __restrict__ in,
                                                 const ushort_t* __restrict__ wtb,
                                                 const float* __restrict__ resid,
                                                 Tout* __restrict__ out,
                                                 int cin, int cout, int wstride,
                                                 int accum) {
  constexpr int ST2 = 136;  // bf16 units per n-row (128 k + 8 pad)
  __shared__ ushort_t bsh[64 * ST2];  // 17408 B
  int tid = threadIdx.x;
  int lane = tid & 63;
  int wid = tid >> 6;
  int lrow = lane & 15;
  int lk = lane >> 4;
  int blk = blockIdx.x;
  int nb = blk & 63;
  int rest = blk >> 6;
  int mb = cout >> 6;
  int m = rest % mb;
  int bi = rest / mb;
  int n0 = nb << 6;
  int o0 = (m << 6) + wid * 16;

  f32x4 acc[4] = {{0.f, 0.f, 0.f, 0.f}, {0.f, 0.f, 0.f, 0.f},
                  {0.f, 0.f, 0.f, 0.f}, {0.f, 0.f, 0.f, 0.f}};

  int nn = tid & 63;   // staging: n within tile
  int wk4 = tid >> 6;  // staging: k-quad selector (wave id)
  for (int kc = 0; kc < cin; kc += 128) {
    // ---- stage In[kc..kc+127][n0..n0+63] -> transposed bf16 LDS [n][k] ----
#pragma unroll
    for (int p = 0; p < 8; p++) {
      int kb = p * 16 + wk4 * 4;
      ushort_t u[4];
#pragma unroll
      for (int j = 0; j < 4; j++) {
        const Tin* src = in + ((size_t)bi * cin + kc + kb + j) * HW_ + n0 + nn;
        if constexpr (sizeof(Tin) == 4) {
          u[j] = f2bu(*(const float*)src);
        } else {
          u[j] = *(const ushort_t*)src;
        }
      }
      us4 w4;
      w4.x = u[0]; w4.y = u[1]; w4.z = u[2]; w4.w = u[3];
      *(us4*)&bsh[nn * ST2 + kb] = w4;
    }
    __syncthreads();
#pragma unroll
    for (int ks = 0; ks < 4; ks++) {
      const ushort_t* wr = wtb + (size_t)(o0 + lrow) * wstride + kc + ks * 32 + lk * 8;
      us4 wlo = *(const us4*)wr;
      us4 whi = *(const us4*)(wr + 4);
      bf16x8 af;
      af[0] = (short)wlo.x; af[1] = (short)wlo.y;
      af[2] = (short)wlo.z; af[3] = (short)wlo.w;
      af[4] = (short)whi.x; af[5] = (short)whi.y;
      af[6] = (short)whi.z; af[7] = (short)whi.w;
#pragma unroll
      for (int s = 0; s < 4; s++) {
        bf16x8 bf_ = *(const bf16x8*)&bsh[(s * 16 + lrow) * ST2 + ks * 32 + lk * 8];
        acc[s] = __builtin_amdgcn_mfma_f32_16x16x32_bf16(af, bf_, acc[s], 0, 0, 0);
      }
    }
    __syncthreads();
  }

  const float* rp = resid ? resid + (size_t)bi * cout * HW_ : nullptr;
  Tout* op = out + (size_t)bi * cout * HW_;
#pragma unroll
  for (int s = 0; s < 4; s++) {
#pragma unroll
    for (int r = 0; r < 4; r++) {
      int o = o0 + lk * 4 + r;
      int n = n0 + s * 16 + lrow;
      size_t off = (size_t)o * HW_ + n;
      float v = acc[s][r];
      if (rp) v += rp[off];
      if (accum) v += toF(op[off]);
      storeF(&op[off], v);
    }
  }
}

// ------- depthwise conv, direct-global vectorized windows, 8 out/thread -------
template <int K>
__global__ __launch_bounds__(256) void dwconv_d(const float* __restrict__ q0,
                                                const float* __restrict__ k0,
                                                const float* __restrict__ v0,
                                                const float* __restrict__ wq_,
                                                const float* __restrict__ wk_,
                                                const float* __restrict__ wv_,
                                                float* __restrict__ qd,
                                                float* __restrict__ kd,
                                                float* __restrict__ vd) {
  constexpr int P = K / 2;
  __shared__ float wsh[K * K];
  int sel = blockIdx.y;
  const float* in = (sel == 0) ? q0 : (sel == 1) ? k0 : v0;
  const float* wgt = (sel == 0) ? wq_ : (sel == 1) ? wk_ : wv_;
  float* outp = (sel == 0) ? qd : (sel == 1) ? kd : vd;
  int blk = blockIdx.x;  // B*C*2
  int half = blk & 1;
  int c = (blk >> 1) & (C_ - 1);
  int bi = blk >> 8;
  int tid = threadIdx.x;

  if (tid < K * K) wsh[tid] = wgt[(size_t)c * K * K + tid];
  __syncthreads();

  int r = tid >> 3;
  int cb = (tid & 7) << 3;
  int y = half * 32 + r;
  const float* plane = in + (size_t)(bi * C_ + c) * HW_;

  float a[8];
#pragma unroll
  for (int o = 0; o < 8; o++) a[o] = 0.f;
#pragma unroll
  for (int dy = 0; dy < K; dy++) {
    int gy = y + dy - P;
    if ((unsigned)gy < 64u) {
      float rv[16];
      loadrow_f(plane + gy * 64, cb, rv);
#pragma unroll
      for (int dx = 0; dx < K; dx++) {
        float wv = wsh[dy * K + dx];
#pragma unroll
        for (int o = 0; o < 8; o++) a[o] = fmaf(rv[o + dx + 4 - P], wv, a[o]);
      }
    }
  }
  float* ob = outp + (size_t)(bi * C_ + c) * HW_ + y * 64 + cb;
  store4f(ob, &a[0]);
  store4f(ob + 4, &a[4]);
}

// ------- FFN depthwise conv + GEGLU gate, 2x8 patch/thread, tanh-gelu -------
template <int K>
__global__ __launch_bounds__(256) void ffn_dwgate_p(const __hip_bfloat16* __restrict__ xin,
                                                    const float* __restrict__ w,
                                                    __hip_bfloat16* __restrict__ gated) {
  constexpr int P = K / 2;
  __shared__ float wsh[2 * K * K];
  int blk = blockIdx.x;  // B*512
  int i = blk & 511;
  int bi = blk >> 9;
  int tid = threadIdx.x;

  if (tid < 2 * K * K) {
    wsh[tid] = (tid < K * K) ? w[(size_t)i * K * K + tid]
                             : w[(size_t)(512 + i) * K * K + (tid - K * K)];
  }
  __syncthreads();

  int r2 = tid >> 3;          // 0..31
  int cb = (tid & 7) << 3;
  int y0 = r2 * 2;
  const __hip_bfloat16* gin = xin + (size_t)(bi * 1024 + i) * HW_;
  const __hip_bfloat16* min_ = gin + (size_t)512 * HW_;

  float ge[16];
  {
    float a0[8], a1[8];
#pragma unroll
    for (int o = 0; o < 8; o++) { a0[o] = 0.f; a1[o] = 0.f; }
#pragma unroll
    for (int rr = 0; rr <= K; rr++) {
      int gy = y0 - P + rr;
      if ((unsigned)gy < 64u) {
        float rv[16];
        loadrow_bf(gin + gy * 64, cb, rv);
        if (rr < K) {
          float wv;
#pragma unroll
          for (int dx = 0; dx < K; dx++) {
            wv = wsh[rr * K + dx];
#pragma unroll
            for (int o = 0; o < 8; o++) a0[o] = fmaf(rv[o + dx + 4 - P], wv, a0[o]);
          }
        }
        if (rr >= 1) {
          float wv;
#pragma unroll
          for (int dx = 0; dx < K; dx++) {
            wv = wsh[(rr - 1) * K + dx];
#pragma unroll
            for (int o = 0; o < 8; o++) a1[o] = fmaf(rv[o + dx + 4 - P], wv, a1[o]);
          }
        }
      }
    }
#pragma unroll
    for (int o = 0; o < 8; o++) { ge[o] = gelu_t(a0[o]); ge[8 + o] = gelu_t(a1[o]); }
  }

  float m0[8], m1[8];
#pragma unroll
  for (int o = 0; o < 8; o++) { m0[o] = 0.f; m1[o] = 0.f; }
#pragma unroll
  for (int rr = 0; rr <= K; rr++) {
    int gy = y0 - P + rr;
    if ((unsigned)gy < 64u) {
      float rv[16];
      loadrow_bf(min_ + gy * 64, cb, rv);
      if (rr < K) {
        float wv;
#pragma unroll
        for (int dx = 0; dx < K; dx++) {
          wv = wsh[K * K + rr * K + dx];
#pragma unroll
          for (int o = 0; o < 8; o++) m0[o] = fmaf(rv[o + dx + 4 - P], wv, m0[o]);
        }
      }
      if (rr >= 1) {
        float wv;
#pragma unroll
        for (int dx = 0; dx < K; dx++) {
          wv = wsh[K * K + (rr - 1) * K + dx];
#pragma unroll
          for (int o = 0; o < 8; o++) m1[o] = fmaf(rv[o + dx + 4 - P], wv, m1[o]);
        }
      }
    }
  }
  __hip_bfloat16* gp = gated + (size_t)(bi * 512 + i) * HW_ + y0 * 64 + cb;
#pragma unroll
  for (int v = 0; v < 2; v++) {
    us4 t;
    t.x = f2bu(ge[v * 4 + 0] * m0[v * 4 + 0]);
    t.y = f2bu(ge[v * 4 + 1] * m0[v * 4 + 1]);
    t.z = f2bu(ge[v * 4 + 2] * m0[v * 4 + 2]);
    t.w = f2bu(ge[v * 4 + 3] * m0[v * 4 + 3]);
    *(us4*)(gp + v * 4) = t;
  }
  gp += 64;
#pragma unroll
  for (int v = 0; v < 2; v++) {
    us4 t;
    t.x = f2bu(ge[8 + v * 4 + 0] * m1[v * 4 + 0]);
    t.y = f2bu(ge[8 + v * 4 + 1] * m1[v * 4 + 1]);
    t.z = f2bu(ge[8 + v * 4 + 2] * m1[v * 4 + 2]);
    t.w = f2bu(ge[8 + v * 4 + 3] * m1[v * 4 + 3]);
    *(us4*)(gp + v * 4) = t;
  }
}

// ---------------- inverse L2 norms of qd and kd rows ----------------
__global__ __launch_bounds__(256) void l2_invnorm(const float* __restrict__ qd,
                                                  const float* __restrict__ kd,
                                                  float* __restrict__ invn) {
  int row = blockIdx.x;  // 0..2047; <1024 -> qd, else kd
  const float* src = (row < 1024) ? (qd + (size_t)row * HW_)
                                  : (kd + (size_t)(row - 1024) * HW_);
  float s = 0.f;
  for (int n = threadIdx.x; n < HW_; n += 256) {
    float v = src[n];
    s = fmaf(v, v, s);
  }
#pragma unroll
  for (int o = 32; o >= 1; o >>= 1) s += __shfl_xor(s, o, 64);
  __shared__ float red[4];
  if ((threadIdx.x & 63) == 0) red[threadIdx.x >> 6] = s;
  __syncthreads();
  if (threadIdx.x == 0) {
    float t = red[0] + red[1] + red[2] + red[3];
    invn[row] = 1.f / fmaxf(sqrtf(t), 1e-12f);
  }
}

// ---------------- attention: partial scores over 256-position chunks ----------------
__global__ __launch_bounds__(256) void attn_score_part(const float* __restrict__ qd,
                                                       const float* __restrict__ kd,
                                                       float* __restrict__ part) {
  constexpr int ST = 258;
  __shared__ float qs[16 * ST];
  __shared__ float ks[16 * ST];
  int bh = blockIdx.x;   // 64
  int ch = blockIdx.y;   // 16 chunks of 256
  int bi = bh >> 3;
  int h = bh & 7;
  int tid = threadIdx.x;
  int c = tid >> 4;
  int d = tid & 15;

  const float* qrow = qd + (size_t)(bi * C_ + h * CH_) * HW_ + ch * 256;
  const float* krow = kd + (size_t)(bi * C_ + h * CH_) * HW_ + ch * 256;
#pragma unroll
  for (int it = 0; it < 4; it++) {
    int idx = tid + it * 256;
    int r = idx >> 6, q4 = idx & 63;
    float4 qv = ((const float4*)(qrow + (size_t)r * HW_))[q4];
    float4 kv = ((const float4*)(krow + (size_t)r * HW_))[q4];
    float* qdst = &qs[r * ST + q4 * 4];
    float* kdst = &ks[r * ST + q4 * 4];
    qdst[0] = qv.x; qdst[1] = qv.y; qdst[2] = qv.z; qdst[3] = qv.w;
    kdst[0] = kv.x; kdst[1] = kv.y; kdst[2] = kv.z; kdst[3] = kv.w;
  }
  __syncthreads();

  const float* qp = &qs[c * ST];
  const float* kp = &ks[d * ST];
  float acc = 0.f;
#pragma unroll 8
  for (int j = 0; j < 256; j++) acc = fmaf(qp[j], kp[j], acc);
  part[((size_t)bh * 16 + ch) * 256 + tid] = acc;
}

// ---------------- attention: reduce partials + softmax ----------------
__global__ __launch_bounds__(256) void attn_softmax(const float* __restrict__ part,
                                                    const float* __restrict__ invn,
                                                    const float* __restrict__ temp,
                                                    float* __restrict__ as_buf) {
  int bh = blockIdx.x;  // 64
  int bi = bh >> 3;
  int h = bh & 7;
  int tid = threadIdx.x;
  int c = tid >> 4;
  int d = tid & 15;
  float s = 0.f;
  const float* pp = part + (size_t)bh * 16 * 256 + tid;
#pragma unroll
  for (int ch = 0; ch < 16; ch++) s += pp[ch * 256];
  float S = s * invn[bi * C_ + h * CH_ + c] * invn[1024 + bi * C_ + h * CH_ + d] *
            temp[h];
  float mx = S;
#pragma unroll
  for (int o = 8; o >= 1; o >>= 1) mx = fmaxf(mx, __shfl_xor(mx, o, 16));
  float e = expf(S - mx);
  float sm = e;
#pragma unroll
  for (int o = 8; o >= 1; o >>= 1) sm += __shfl_xor(sm, o, 16);
  as_buf[(size_t)bh * 256 + tid] = e / sm;
}

// ---------------- attention: PV over 256-position chunks ----------------
__global__ __launch_bounds__(256) void attn_pv(const float* __restrict__ vd,
                                               const float* __restrict__ as_buf,
                                               float* __restrict__ osb) {
  __shared__ float as[16][17];
  int bh = blockIdx.x;  // 64
  int ch = blockIdx.y;  // 16
  int bi = bh >> 3;
  int h = bh & 7;
  int tid = threadIdx.x;
  if (tid < 256) {
    int cc = tid >> 4, dd = tid & 15;
    as[cc][dd] = as_buf[(size_t)bh * 256 + tid];
  }
  __syncthreads();

  int n = ch * 256 + tid;
  const float* vrow = vd + (size_t)(bi * C_ + h * CH_) * HW_ + n;
  float o_[16];
#pragma unroll
  for (int cc = 0; cc < 16; cc++) o_[cc] = 0.f;
#pragma unroll
  for (int dd = 0; dd < 16; dd++) {
    float vv = vrow[(size_t)dd * HW_];
#pragma unroll
    for (int cc = 0; cc < 16; cc++) o_[cc] = fmaf(as[cc][dd], vv, o_[cc]);
  }
  float* ob = osb + (size_t)(bi * C_ + h * CH_) * HW_ + n;
#pragma unroll
  for (int cc = 0; cc < 16; cc++) ob[(size_t)cc * HW_] = o_[cc];
}

extern "C" void kernel_launch(void* const* d_in, const int* in_sizes, int n_in,
                              void* d_out, int out_size, void* d_ws, size_t ws_size,
                              hipStream_t stream) {
  const float* x = (const float*)d_in[0];
  const float* ln1_w = (const float*)d_in[1];
  const float* ln1_b = (const float*)d_in[2];
  const float* temp = (const float*)d_in[3];
  const float* wq = (const float*)d_in[4];
  const float* wk = (const float*)d_in[5];
  const float* wv = (const float*)d_in[6];
  const float* dw[9];
  for (int i = 0; i < 9; i++) dw[i] = (const float*)d_in[7 + i];
  const float* attn_po = (const float*)d_in[16];
  const float* ln2_w = (const float*)d_in[17];
  const float* ln2_b = (const float*)d_in[18];
  const float* ffn_in = (const float*)d_in[19];
  const float* ffn_dw[3] = {(const float*)d_in[20], (const float*)d_in[21],
                            (const float*)d_in[22]};
  const float* ffn_po = (const float*)d_in[23];
  float* out = (float*)d_out;

  // ---- workspace layout: peak ~129 MiB, lifetime-aliased ----
  const size_t MB = (size_t)1 << 20;
  char* wsb = (char*)d_ws;
  float* xn = (float*)(wsb + 0 * MB);
  float* q0 = (float*)(wsb + 16 * MB);
  float* k0 = (float*)(wsb + 32 * MB);
  float* v0 = (float*)(wsb + 48 * MB);
  float* qd = (float*)(wsb + 64 * MB);
  float* kd = (float*)(wsb + 80 * MB);
  float* vd = (float*)(wsb + 96 * MB);
  float* x2 = (float*)(wsb + 112 * MB);
  float* invn = (float*)(wsb + 128 * MB);               // 8 KiB
  float* as_buf = (float*)(wsb + 128 * MB + 8 * 1024);  // 64 KiB
  ushort_t* wbuf = (ushort_t*)(wsb + 128 * MB + 80 * 1024);  // 832 KiB bf16 weights
  float* osb = xn;
  float* xn2 = xn;
  float* part = xn;  // 4 MB partial-score buffer; dead before osb is written
  __hip_bfloat16* xin = (__hip_bfloat16*)(wsb + 16 * MB);    // 64 MB
  __hip_bfloat16* gated = (__hip_bfloat16*)(wsb + 80 * MB);  // 32 MB

  const ushort_t* wb_q = wbuf;
  const ushort_t* wb_k = wbuf + 16384;
  const ushort_t* wb_v = wbuf + 32768;
  const ushort_t* wb_apo = wbuf + 49152;
  const ushort_t* wb_fin = wbuf + 98304;
  const ushort_t* wb_fpo = wbuf + 229376;

  const int ln_grid = (B_ * HW_) / 256;                  // 128
  const int g128 = B_ * (C_ / 64) * 64;                  // 1024 (cout=128)
  const int g1024 = B_ * (1024 / 64) * 64;               // 8192 (cout=1024)
  const dim3 dwt_grid(B_ * C_ * 2, 3);                   // 2048 x 3
  const int ffg_grid = B_ * 512;                         // 4096
  const dim3 att_grid(B_ * HEADS_, 16);                  // 64 x 16

  // ---- weight prep (bf16) ----
  cvt_w<<<1664, 256, 0, stream>>>(wq, wk, wv, attn_po, ffn_in, ffn_po, wbuf);

  // ---- attention branch ----
  ln_ch<<<ln_grid, 256, 0, stream>>>(x, ln1_w, ln1_b, xn);
  conv1x1_m<float, float><<<g128, 256, 0, stream>>>(xn, wb_q, nullptr, q0, C_, C_, C_, 0);
  conv1x1_m<float, float><<<g128, 256, 0, stream>>>(xn, wb_k, nullptr, k0, C_, C_, C_, 0);
  conv1x1_m<float, float><<<g128, 256, 0, stream>>>(xn, wb_v, nullptr, v0, C_, C_, C_, 0);

  for (int s = 0; s < 3; s++) {
    if (s == 0)
      dwconv_d<3><<<dwt_grid, 256, 0, stream>>>(q0, k0, v0, dw[0], dw[1], dw[2], qd, kd, vd);
    else if (s == 1)
      dwconv_d<5><<<dwt_grid, 256, 0, stream>>>(q0, k0, v0, dw[3], dw[4], dw[5], qd, kd, vd);
    else
      dwconv_d<7><<<dwt_grid, 256, 0, stream>>>(q0, k0, v0, dw[6], dw[7], dw[8], qd, kd, vd);
    l2_invnorm<<<2048, 256, 0, stream>>>(qd, kd, invn);
    attn_score_part<<<att_grid, 256, 0, stream>>>(qd, kd, part);
    attn_softmax<<<B_ * HEADS_, 256, 0, stream>>>(part, invn, temp, as_buf);
    attn_pv<<<att_grid, 256, 0, stream>>>(vd, as_buf, osb);
    conv1x1_m<float, float><<<g128, 256, 0, stream>>>(
        osb, wb_apo + s * C_, (s == 0) ? x : nullptr, x2, C_, C_, 3 * C_, s == 0 ? 0 : 1);
  }

  // ---- FFN branch ----
  ln_ch<<<ln_grid, 256, 0, stream>>>(x2, ln2_w, ln2_b, xn2);
  conv1x1_m<float, __hip_bfloat16><<<g1024, 256, 0, stream>>>(
      xn2, wb_fin, nullptr, xin, C_, 1024, C_, 0);

  for (int s = 0; s < 3; s++) {
    if (s == 0)
      ffn_dwgate_p<3><<<ffg_grid, 256, 0, stream>>>(xin, ffn_dw[0], gated);
    else if (s == 1)
      ffn_dwgate_p<5><<<ffg_grid, 256, 0, stream>>>(xin, ffn_dw[1], gated);
    else
      ffn_dwgate_p<7><<<ffg_grid, 256, 0, stream>>>(xin, ffn_dw[2], gated);
    conv1x1_m<__hip_bfloat16, float><<<g128, 256, 0, stream>>>(
        gated, wb_fpo + s * 512, (s == 0) ? x2 : nullptr, out, 512, C_, 3 * HID_,
        s == 0 ? 0 : 1);
  }
  (void)in_sizes; (void)n_in; (void)out_size; (void)ws_size;
}

// Round 15
// 464.328 us; speedup vs baseline: 1.1777x; 1.1777x over previous
//
#include <hip/hip_runtime.h>
#include <hip/hip_bf16.h>
#include <math.h>

#define B_ 8
#define C_ 128
#define H_ 64
#define W_ 64
#define HW_ 4096
#define HEADS_ 8
#define CH_ 16
#define HID_ 512

typedef unsigned short ushort_t;
struct __attribute__((aligned(8))) us4 { ushort_t x, y, z, w; };

typedef __attribute__((ext_vector_type(8))) short bf16x8;
typedef __attribute__((ext_vector_type(4))) float f32x4;

__device__ __forceinline__ float bf2f(ushort_t u) {
  return __uint_as_float(((unsigned int)u) << 16);
}
__device__ __forceinline__ ushort_t f2bu(float f) {
  __hip_bfloat16 h = __float2bfloat16(f);
  return *reinterpret_cast<ushort_t*>(&h);
}
__device__ __forceinline__ float toF(float v) { return v; }
__device__ __forceinline__ float toF(__hip_bfloat16 v) { return __bfloat162float(v); }
__device__ __forceinline__ float toF(ushort_t v) { return bf2f(v); }
__device__ __forceinline__ void storeF(float* p, float v) { *p = v; }
__device__ __forceinline__ void storeF(__hip_bfloat16* p, float v) { *p = __float2bfloat16(v); }
__device__ __forceinline__ void storeF(ushort_t* p, float v) { *p = f2bu(v); }

// tanh-GELU: max dev from exact erf-GELU ~1e-3, straight-line
__device__ __forceinline__ float gelu_t(float x) {
  float z = 0.7978845608f * fmaf(0.044715f * x, x * x, x);
  float e = __expf(2.f * z);
  float th = 1.f - 2.f / (e + 1.f);
  return 0.5f * x * (1.f + th);
}

// ---------------- LayerNorm over channel dim (bf16 out) ----------------
__global__ __launch_bounds__(256) void ln_ch(const float* __restrict__ x,
                                             const float* __restrict__ w,
                                             const float* __restrict__ b,
                                             ushort_t* __restrict__ out) {
  int p = blockIdx.x * 256 + threadIdx.x;  // over B*HW
  int bi = p >> 12;
  int pos = p & (HW_ - 1);
  const float* xb = x + (size_t)bi * C_ * HW_ + pos;
  float s = 0.f, ss = 0.f;
  for (int c = 0; c < C_; c++) {
    float v = xb[(size_t)c * HW_];
    s += v;
    ss = fmaf(v, v, ss);
  }
  float mu = s * (1.f / C_);
  float var = ss * (1.f / C_) - mu * mu;
  float inv = rsqrtf(var + 1e-5f);
  ushort_t* ob = out + (size_t)bi * C_ * HW_ + pos;
  for (int c = 0; c < C_; c++) {
    ob[(size_t)c * HW_] = f2bu((xb[(size_t)c * HW_] - mu) * inv * w[c] + b[c]);
  }
}

// ---------------- weight prep: fp32 -> bf16, all six matrices ----------------
__global__ __launch_bounds__(256) void cvt_w(const float* __restrict__ wq,
                                             const float* __restrict__ wk,
                                             const float* __restrict__ wv,
                                             const float* __restrict__ apo,
                                             const float* __restrict__ fin,
                                             const float* __restrict__ fpo,
                                             ushort_t* __restrict__ dst) {
  int id = blockIdx.x * 256 + threadIdx.x;
  const float* src;
  int off;
  if (id < 16384) { src = wq; off = id; }
  else if (id < 32768) { src = wk; off = id - 16384; }
  else if (id < 49152) { src = wv; off = id - 32768; }
  else if (id < 98304) { src = apo; off = id - 49152; }
  else if (id < 229376) { src = fin; off = id - 98304; }
  else if (id < 425984) { src = fpo; off = id - 229376; }
  else return;
  dst[id] = f2bu(src[off]);
}

// ---------------- vector load/store helpers ----------------
__device__ __forceinline__ void store4f(float* p, const float* v) {
  float4 t; t.x = v[0]; t.y = v[1]; t.z = v[2]; t.w = v[3];
  *(float4*)p = t;
}

// load 16-elem window rv[j] = row[cb-4+j], zero-padded outside [0,64)
__device__ __forceinline__ void loadrow_bf(const ushort_t* __restrict__ rowp,
                                           int cb, float* rv) {
#pragma unroll
  for (int b = 0; b < 4; b++) {
    int co = cb - 4 + b * 4;
    if ((unsigned)co <= 60u) {
      us4 t = *(const us4*)(rowp + co);
      rv[b * 4 + 0] = bf2f(t.x); rv[b * 4 + 1] = bf2f(t.y);
      rv[b * 4 + 2] = bf2f(t.z); rv[b * 4 + 3] = bf2f(t.w);
    } else {
      rv[b * 4 + 0] = 0.f; rv[b * 4 + 1] = 0.f;
      rv[b * 4 + 2] = 0.f; rv[b * 4 + 3] = 0.f;
    }
  }
}

// ------- conv1x1 as bf16 MFMA GEMM: Out[cout][HW] = W[cout][cin] @ In[cin][HW] -------
// Transposed LDS tile [n][k] (R14); B-frag = one ds_read_b128.
template <typename Tin, typename Tout>
__global__ __launch_bounds__(256) void conv1x1_m(const Tin* __restrict__ in,
                                                 const ushort_t* __restrict__ wtb,
                                                 const float* __restrict__ resid,
                                                 Tout* __restrict__ out,
                                                 int cin, int cout, int wstride,
                                                 int accum) {
  constexpr int ST2 = 136;  // bf16 units per n-row (128 k + 8 pad)
  __shared__ ushort_t bsh[64 * ST2];
  int tid = threadIdx.x;
  int lane = tid & 63;
  int wid = tid >> 6;
  int lrow = lane & 15;
  int lk = lane >> 4;
  int blk = blockIdx.x;
  int nb = blk & 63;
  int rest = blk >> 6;
  int mb = cout >> 6;
  int m = rest % mb;
  int bi = rest / mb;
  int n0 = nb << 6;
  int o0 = (m << 6) + wid * 16;

  f32x4 acc[4] = {{0.f, 0.f, 0.f, 0.f}, {0.f, 0.f, 0.f, 0.f},
                  {0.f, 0.f, 0.f, 0.f}, {0.f, 0.f, 0.f, 0.f}};

  int nn = tid & 63;   // staging: n within tile
  int wk4 = tid >> 6;  // staging: k-quad selector
  for (int kc = 0; kc < cin; kc += 128) {
#pragma unroll
    for (int p = 0; p < 8; p++) {
      int kb = p * 16 + wk4 * 4;
      ushort_t u[4];
#pragma unroll
      for (int j = 0; j < 4; j++) {
        const Tin* src = in + ((size_t)bi * cin + kc + kb + j) * HW_ + n0 + nn;
        if constexpr (sizeof(Tin) == 4) {
          u[j] = f2bu(*(const float*)src);
        } else {
          u[j] = *(const ushort_t*)src;
        }
      }
      us4 w4;
      w4.x = u[0]; w4.y = u[1]; w4.z = u[2]; w4.w = u[3];
      *(us4*)&bsh[nn * ST2 + kb] = w4;
    }
    __syncthreads();
#pragma unroll
    for (int ks = 0; ks < 4; ks++) {
      const ushort_t* wr = wtb + (size_t)(o0 + lrow) * wstride + kc + ks * 32 + lk * 8;
      us4 wlo = *(const us4*)wr;
      us4 whi = *(const us4*)(wr + 4);
      bf16x8 af;
      af[0] = (short)wlo.x; af[1] = (short)wlo.y;
      af[2] = (short)wlo.z; af[3] = (short)wlo.w;
      af[4] = (short)whi.x; af[5] = (short)whi.y;
      af[6] = (short)whi.z; af[7] = (short)whi.w;
#pragma unroll
      for (int s = 0; s < 4; s++) {
        bf16x8 bf_ = *(const bf16x8*)&bsh[(s * 16 + lrow) * ST2 + ks * 32 + lk * 8];
        acc[s] = __builtin_amdgcn_mfma_f32_16x16x32_bf16(af, bf_, acc[s], 0, 0, 0);
      }
    }
    __syncthreads();
  }

  const float* rp = resid ? resid + (size_t)bi * cout * HW_ : nullptr;
  Tout* op = out + (size_t)bi * cout * HW_;
#pragma unroll
  for (int s = 0; s < 4; s++) {
#pragma unroll
    for (int r = 0; r < 4; r++) {
      int o = o0 + lk * 4 + r;
      int n = n0 + s * 16 + lrow;
      size_t off = (size_t)o * HW_ + n;
      float v = acc[s][r];
      if (rp) v += rp[off];
      if (accum) v += toF(op[off]);
      storeF(&op[off], v);
    }
  }
}

// ------- depthwise conv (bf16 in/out), fused L2 sum-of-squares for q,k -------
template <int K>
__global__ __launch_bounds__(256) void dwconv_d(const ushort_t* __restrict__ q0,
                                                const ushort_t* __restrict__ k0,
                                                const ushort_t* __restrict__ v0,
                                                const float* __restrict__ wq_,
                                                const float* __restrict__ wk_,
                                                const float* __restrict__ wv_,
                                                ushort_t* __restrict__ qd,
                                                ushort_t* __restrict__ kd,
                                                ushort_t* __restrict__ vd,
                                                float* __restrict__ sumsq_s) {
  constexpr int P = K / 2;
  __shared__ float wsh[K * K];
  __shared__ float red[4];
  int sel = blockIdx.y;
  const ushort_t* in = (sel == 0) ? q0 : (sel == 1) ? k0 : v0;
  const float* wgt = (sel == 0) ? wq_ : (sel == 1) ? wk_ : wv_;
  ushort_t* outp = (sel == 0) ? qd : (sel == 1) ? kd : vd;
  int blk = blockIdx.x;  // B*C*2
  int half = blk & 1;
  int c = (blk >> 1) & (C_ - 1);
  int bi = blk >> 8;
  int tid = threadIdx.x;

  if (tid < K * K) wsh[tid] = wgt[(size_t)c * K * K + tid];
  __syncthreads();

  int r = tid >> 3;
  int cb = (tid & 7) << 3;
  int y = half * 32 + r;
  const ushort_t* plane = in + (size_t)(bi * C_ + c) * HW_;

  float a[8];
#pragma unroll
  for (int o = 0; o < 8; o++) a[o] = 0.f;
#pragma unroll
  for (int dy = 0; dy < K; dy++) {
    int gy = y + dy - P;
    if ((unsigned)gy < 64u) {
      float rv[16];
      loadrow_bf(plane + gy * 64, cb, rv);
#pragma unroll
      for (int dx = 0; dx < K; dx++) {
        float wv = wsh[dy * K + dx];
#pragma unroll
        for (int o = 0; o < 8; o++) a[o] = fmaf(rv[o + dx + 4 - P], wv, a[o]);
      }
    }
  }
  ushort_t* ob = outp + (size_t)(bi * C_ + c) * HW_ + y * 64 + cb;
  us4 t0, t1;
  t0.x = f2bu(a[0]); t0.y = f2bu(a[1]); t0.z = f2bu(a[2]); t0.w = f2bu(a[3]);
  t1.x = f2bu(a[4]); t1.y = f2bu(a[5]); t1.z = f2bu(a[6]); t1.w = f2bu(a[7]);
  *(us4*)ob = t0;
  *(us4*)(ob + 4) = t1;

  // fused row sum-of-squares (from fp32 accumulators) for q (sel=0), k (sel=1)
  float ssq = 0.f;
#pragma unroll
  for (int o = 0; o < 8; o++) ssq = fmaf(a[o], a[o], ssq);
#pragma unroll
  for (int off = 32; off >= 1; off >>= 1) ssq += __shfl_xor(ssq, off, 64);
  if ((tid & 63) == 0) red[tid >> 6] = ssq;
  __syncthreads();
  if (tid == 0 && sel < 2) {
    atomicAdd(&sumsq_s[sel * 1024 + bi * C_ + c], red[0] + red[1] + red[2] + red[3]);
  }
}

// ------- FFN depthwise conv + GEGLU gate, 2x8 patch/thread, tanh-gelu -------
template <int K>
__global__ __launch_bounds__(256) void ffn_dwgate_p(const ushort_t* __restrict__ xin,
                                                    const float* __restrict__ w,
                                                    ushort_t* __restrict__ gated) {
  constexpr int P = K / 2;
  __shared__ float wsh[2 * K * K];
  int blk = blockIdx.x;  // B*512
  int i = blk & 511;
  int bi = blk >> 9;
  int tid = threadIdx.x;

  if (tid < 2 * K * K) {
    wsh[tid] = (tid < K * K) ? w[(size_t)i * K * K + tid]
                             : w[(size_t)(512 + i) * K * K + (tid - K * K)];
  }
  __syncthreads();

  int r2 = tid >> 3;          // 0..31
  int cb = (tid & 7) << 3;
  int y0 = r2 * 2;
  const ushort_t* gin = xin + (size_t)(bi * 1024 + i) * HW_;
  const ushort_t* min_ = gin + (size_t)512 * HW_;

  float ge[16];
  {
    float a0[8], a1[8];
#pragma unroll
    for (int o = 0; o < 8; o++) { a0[o] = 0.f; a1[o] = 0.f; }
#pragma unroll
    for (int rr = 0; rr <= K; rr++) {
      int gy = y0 - P + rr;
      if ((unsigned)gy < 64u) {
        float rv[16];
        loadrow_bf(gin + gy * 64, cb, rv);
        if (rr < K) {
          float wv;
#pragma unroll
          for (int dx = 0; dx < K; dx++) {
            wv = wsh[rr * K + dx];
#pragma unroll
            for (int o = 0; o < 8; o++) a0[o] = fmaf(rv[o + dx + 4 - P], wv, a0[o]);
          }
        }
        if (rr >= 1) {
          float wv;
#pragma unroll
          for (int dx = 0; dx < K; dx++) {
            wv = wsh[(rr - 1) * K + dx];
#pragma unroll
            for (int o = 0; o < 8; o++) a1[o] = fmaf(rv[o + dx + 4 - P], wv, a1[o]);
          }
        }
      }
    }
#pragma unroll
    for (int o = 0; o < 8; o++) { ge[o] = gelu_t(a0[o]); ge[8 + o] = gelu_t(a1[o]); }
  }

  float m0[8], m1[8];
#pragma unroll
  for (int o = 0; o < 8; o++) { m0[o] = 0.f; m1[o] = 0.f; }
#pragma unroll
  for (int rr = 0; rr <= K; rr++) {
    int gy = y0 - P + rr;
    if ((unsigned)gy < 64u) {
      float rv[16];
      loadrow_bf(min_ + gy * 64, cb, rv);
      if (rr < K) {
        float wv;
#pragma unroll
        for (int dx = 0; dx < K; dx++) {
          wv = wsh[K * K + rr * K + dx];
#pragma unroll
          for (int o = 0; o < 8; o++) m0[o] = fmaf(rv[o + dx + 4 - P], wv, m0[o]);
        }
      }
      if (rr >= 1) {
        float wv;
#pragma unroll
        for (int dx = 0; dx < K; dx++) {
          wv = wsh[K * K + (rr - 1) * K + dx];
#pragma unroll
          for (int o = 0; o < 8; o++) m1[o] = fmaf(rv[o + dx + 4 - P], wv, m1[o]);
        }
      }
    }
  }
  ushort_t* gp = gated + (size_t)(bi * 512 + i) * HW_ + y0 * 64 + cb;
#pragma unroll
  for (int v = 0; v < 2; v++) {
    us4 t;
    t.x = f2bu(ge[v * 4 + 0] * m0[v * 4 + 0]);
    t.y = f2bu(ge[v * 4 + 1] * m0[v * 4 + 1]);
    t.z = f2bu(ge[v * 4 + 2] * m0[v * 4 + 2]);
    t.w = f2bu(ge[v * 4 + 3] * m0[v * 4 + 3]);
    *(us4*)(gp + v * 4) = t;
  }
  gp += 64;
#pragma unroll
  for (int v = 0; v < 2; v++) {
    us4 t;
    t.x = f2bu(ge[8 + v * 4 + 0] * m1[v * 4 + 0]);
    t.y = f2bu(ge[8 + v * 4 + 1] * m1[v * 4 + 1]);
    t.z = f2bu(ge[8 + v * 4 + 2] * m1[v * 4 + 2]);
    t.w = f2bu(ge[8 + v * 4 + 3] * m1[v * 4 + 3]);
    *(us4*)(gp + v * 4) = t;
  }
}

// ---------------- attention: partial scores over 256-position chunks (bf16 in) ----------------
__global__ __launch_bounds__(256) void attn_score_part(const ushort_t* __restrict__ qd,
                                                       const ushort_t* __restrict__ kd,
                                                       float* __restrict__ part) {
  constexpr int ST = 258;
  __shared__ float qs[16 * ST];
  __shared__ float ks[16 * ST];
  int bh = blockIdx.x;   // 64
  int ch = blockIdx.y;   // 16 chunks of 256
  int bi = bh >> 3;
  int h = bh & 7;
  int tid = threadIdx.x;
  int c = tid >> 4;
  int d = tid & 15;

  const ushort_t* qrow = qd + (size_t)(bi * C_ + h * CH_) * HW_ + ch * 256;
  const ushort_t* krow = kd + (size_t)(bi * C_ + h * CH_) * HW_ + ch * 256;
#pragma unroll
  for (int it = 0; it < 4; it++) {
    int idx = tid + it * 256;
    int r = idx >> 6, q4 = idx & 63;
    us4 qv = *(const us4*)(qrow + (size_t)r * HW_ + q4 * 4);
    us4 kv = *(const us4*)(krow + (size_t)r * HW_ + q4 * 4);
    float* qdst = &qs[r * ST + q4 * 4];
    float* kdst = &ks[r * ST + q4 * 4];
    qdst[0] = bf2f(qv.x); qdst[1] = bf2f(qv.y); qdst[2] = bf2f(qv.z); qdst[3] = bf2f(qv.w);
    kdst[0] = bf2f(kv.x); kdst[1] = bf2f(kv.y); kdst[2] = bf2f(kv.z); kdst[3] = bf2f(kv.w);
  }
  __syncthreads();

  const float* qp = &qs[c * ST];
  const float* kp = &ks[d * ST];
  float acc = 0.f;
#pragma unroll 8
  for (int j = 0; j < 256; j++) acc = fmaf(qp[j], kp[j], acc);
  part[((size_t)bh * 16 + ch) * 256 + tid] = acc;
}

// ---------------- attention: reduce partials + softmax (inline inv-norms) ----------------
__global__ __launch_bounds__(256) void attn_softmax(const float* __restrict__ part,
                                                    const float* __restrict__ sumsq_s,
                                                    const float* __restrict__ temp,
                                                    float* __restrict__ as_buf) {
  int bh = blockIdx.x;  // 64
  int bi = bh >> 3;
  int h = bh & 7;
  int tid = threadIdx.x;
  int c = tid >> 4;
  int d = tid & 15;
  float s = 0.f;
  const float* pp = part + (size_t)bh * 16 * 256 + tid;
#pragma unroll
  for (int ch = 0; ch < 16; ch++) s += pp[ch * 256];
  float sq = sumsq_s[bi * C_ + h * CH_ + c];
  float sk = sumsq_s[1024 + bi * C_ + h * CH_ + d];
  float invq = 1.f / fmaxf(sqrtf(sq), 1e-12f);
  float invk = 1.f / fmaxf(sqrtf(sk), 1e-12f);
  float S = s * invq * invk * temp[h];
  float mx = S;
#pragma unroll
  for (int o = 8; o >= 1; o >>= 1) mx = fmaxf(mx, __shfl_xor(mx, o, 16));
  float e = expf(S - mx);
  float sm = e;
#pragma unroll
  for (int o = 8; o >= 1; o >>= 1) sm += __shfl_xor(sm, o, 16);
  as_buf[(size_t)bh * 256 + tid] = e / sm;
}

// ---------------- attention: PV over 256-position chunks (bf16 V, bf16 out) ----------------
__global__ __launch_bounds__(256) void attn_pv(const ushort_t* __restrict__ vd,
                                               const float* __restrict__ as_buf,
                                               ushort_t* __restrict__ osb) {
  __shared__ float as[16][17];
  int bh = blockIdx.x;  // 64
  int ch = blockIdx.y;  // 16
  int bi = bh >> 3;
  int h = bh & 7;
  int tid = threadIdx.x;
  if (tid < 256) {
    int cc = tid >> 4, dd = tid & 15;
    as[cc][dd] = as_buf[(size_t)bh * 256 + tid];
  }
  __syncthreads();

  int n = ch * 256 + tid;
  const ushort_t* vrow = vd + (size_t)(bi * C_ + h * CH_) * HW_ + n;
  float o_[16];
#pragma unroll
  for (int cc = 0; cc < 16; cc++) o_[cc] = 0.f;
#pragma unroll
  for (int dd = 0; dd < 16; dd++) {
    float vv = bf2f(vrow[(size_t)dd * HW_]);
#pragma unroll
    for (int cc = 0; cc < 16; cc++) o_[cc] = fmaf(as[cc][dd], vv, o_[cc]);
  }
  ushort_t* ob = osb + (size_t)(bi * C_ + h * CH_) * HW_ + n;
#pragma unroll
  for (int cc = 0; cc < 16; cc++) ob[(size_t)cc * HW_] = f2bu(o_[cc]);
}

extern "C" void kernel_launch(void* const* d_in, const int* in_sizes, int n_in,
                              void* d_out, int out_size, void* d_ws, size_t ws_size,
                              hipStream_t stream) {
  const float* x = (const float*)d_in[0];
  const float* ln1_w = (const float*)d_in[1];
  const float* ln1_b = (const float*)d_in[2];
  const float* temp = (const float*)d_in[3];
  const float* wq = (const float*)d_in[4];
  const float* wk = (const float*)d_in[5];
  const float* wv = (const float*)d_in[6];
  const float* dw[9];
  for (int i = 0; i < 9; i++) dw[i] = (const float*)d_in[7 + i];
  const float* attn_po = (const float*)d_in[16];
  const float* ln2_w = (const float*)d_in[17];
  const float* ln2_b = (const float*)d_in[18];
  const float* ffn_in = (const float*)d_in[19];
  const float* ffn_dw[3] = {(const float*)d_in[20], (const float*)d_in[21],
                            (const float*)d_in[22]};
  const float* ffn_po = (const float*)d_in[23];
  float* out = (float*)d_out;

  // ---- workspace layout (bf16 intermediates), lifetime-aliased ----
  const size_t MB = (size_t)1 << 20;
  char* wsb = (char*)d_ws;
  ushort_t* xnb = (ushort_t*)(wsb + 0 * MB);    // 8 MB (LN out; later FFN LN out)
  float* part = (float*)(wsb + 0 * MB);          // 4 MB (aliases xnb after qkv consumed)
  ushort_t* osb = (ushort_t*)(wsb + 8 * MB);     // 8 MB attn per-scale output
  ushort_t* q0b = (ushort_t*)(wsb + 16 * MB);    // 8 MB each
  ushort_t* k0b = (ushort_t*)(wsb + 32 * MB);
  ushort_t* v0b = (ushort_t*)(wsb + 48 * MB);
  ushort_t* qdb = (ushort_t*)(wsb + 64 * MB);
  ushort_t* kdb = (ushort_t*)(wsb + 80 * MB);
  ushort_t* vdb = (ushort_t*)(wsb + 96 * MB);
  float* x2 = (float*)(wsb + 112 * MB);          // 16 MB fp32 residual stream
  float* as_buf = (float*)(wsb + 128 * MB);                  // 64 KiB
  float* sumsq = (float*)(wsb + 128 * MB + 64 * 1024);       // 24 KiB (3 scales x 2048)
  ushort_t* wbuf = (ushort_t*)(wsb + 128 * MB + 96 * 1024);  // 832 KiB bf16 weights
  ushort_t* xin = (ushort_t*)(wsb + 16 * MB);    // 64 MB, aliases q0..qd (dead in FFN)
  ushort_t* gated = (ushort_t*)(wsb + 80 * MB);  // 32 MB, aliases kd,vd

  const ushort_t* wb_q = wbuf;
  const ushort_t* wb_k = wbuf + 16384;
  const ushort_t* wb_v = wbuf + 32768;
  const ushort_t* wb_apo = wbuf + 49152;
  const ushort_t* wb_fin = wbuf + 98304;
  const ushort_t* wb_fpo = wbuf + 229376;

  const int ln_grid = (B_ * HW_) / 256;                  // 128
  const int g128 = B_ * (C_ / 64) * 64;                  // 1024 (cout=128)
  const int g1024 = B_ * (1024 / 64) * 64;               // 8192 (cout=1024)
  const dim3 dwt_grid(B_ * C_ * 2, 3);                   // 2048 x 3
  const int ffg_grid = B_ * 512;                         // 4096
  const dim3 att_grid(B_ * HEADS_, 16);                  // 64 x 16

  // ---- prep: zero sumsq, convert weights to bf16 ----
  hipMemsetAsync(sumsq, 0, 3 * 2048 * sizeof(float), stream);
  cvt_w<<<1664, 256, 0, stream>>>(wq, wk, wv, attn_po, ffn_in, ffn_po, wbuf);

  // ---- attention branch ----
  ln_ch<<<ln_grid, 256, 0, stream>>>(x, ln1_w, ln1_b, xnb);
  conv1x1_m<ushort_t, ushort_t><<<g128, 256, 0, stream>>>(xnb, wb_q, nullptr, q0b, C_, C_, C_, 0);
  conv1x1_m<ushort_t, ushort_t><<<g128, 256, 0, stream>>>(xnb, wb_k, nullptr, k0b, C_, C_, C_, 0);
  conv1x1_m<ushort_t, ushort_t><<<g128, 256, 0, stream>>>(xnb, wb_v, nullptr, v0b, C_, C_, C_, 0);

  for (int s = 0; s < 3; s++) {
    float* sumsq_s = sumsq + s * 2048;
    if (s == 0)
      dwconv_d<3><<<dwt_grid, 256, 0, stream>>>(q0b, k0b, v0b, dw[0], dw[1], dw[2],
                                                qdb, kdb, vdb, sumsq_s);
    else if (s == 1)
      dwconv_d<5><<<dwt_grid, 256, 0, stream>>>(q0b, k0b, v0b, dw[3], dw[4], dw[5],
                                                qdb, kdb, vdb, sumsq_s);
    else
      dwconv_d<7><<<dwt_grid, 256, 0, stream>>>(q0b, k0b, v0b, dw[6], dw[7], dw[8],
                                                qdb, kdb, vdb, sumsq_s);
    attn_score_part<<<att_grid, 256, 0, stream>>>(qdb, kdb, part);
    attn_softmax<<<B_ * HEADS_, 256, 0, stream>>>(part, sumsq_s, temp, as_buf);
    attn_pv<<<att_grid, 256, 0, stream>>>(vdb, as_buf, osb);
    conv1x1_m<ushort_t, float><<<g128, 256, 0, stream>>>(
        osb, wb_apo + s * C_, (s == 0) ? x : nullptr, x2, C_, C_, 3 * C_, s == 0 ? 0 : 1);
  }

  // ---- FFN branch ----
  ln_ch<<<ln_grid, 256, 0, stream>>>(x2, ln2_w, ln2_b, xnb);
  conv1x1_m<ushort_t, ushort_t><<<g1024, 256, 0, stream>>>(
      xnb, wb_fin, nullptr, xin, C_, 1024, C_, 0);

  for (int s = 0; s < 3; s++) {
    if (s == 0)
      ffn_dwgate_p<3><<<ffg_grid, 256, 0, stream>>>(xin, ffn_dw[0], gated);
    else if (s == 1)
      ffn_dwgate_p<5><<<ffg_grid, 256, 0, stream>>>(xin, ffn_dw[1], gated);
    else
      ffn_dwgate_p<7><<<ffg_grid, 256, 0, stream>>>(xin, ffn_dw[2], gated);
    conv1x1_m<ushort_t, float><<<g128, 256, 0, stream>>>(
        gated, wb_fpo + s * 512, (s == 0) ? x2 : nullptr, out, 512, C_, 3 * HID_,
        s == 0 ? 0 : 1);
  }
  (void)in_sizes; (void)n_in; (void)out_size; (void)ws_size;
}

// Round 16
// 441.654 us; speedup vs baseline: 1.2382x; 1.0513x over previous
//
#include <hip/hip_runtime.h>
#include <hip/hip_bf16.h>
#include <math.h>

#define B_ 8
#define C_ 128
#define H_ 64
#define W_ 64
#define HW_ 4096
#define HEADS_ 8
#define CH_ 16
#define HID_ 512

typedef unsigned short ushort_t;
struct __attribute__((aligned(8))) us4 { ushort_t x, y, z, w; };

typedef __attribute__((ext_vector_type(8))) short bf16x8;
typedef __attribute__((ext_vector_type(4))) float f32x4;

__device__ __forceinline__ float bf2f(ushort_t u) {
  return __uint_as_float(((unsigned int)u) << 16);
}
__device__ __forceinline__ ushort_t f2bu(float f) {
  __hip_bfloat16 h = __float2bfloat16(f);
  return *reinterpret_cast<ushort_t*>(&h);
}
__device__ __forceinline__ float toF(float v) { return v; }
__device__ __forceinline__ float toF(ushort_t v) { return bf2f(v); }
__device__ __forceinline__ void storeF(float* p, float v) { *p = v; }
__device__ __forceinline__ void storeF(ushort_t* p, float v) { *p = f2bu(v); }

// tanh-GELU: max dev from exact erf-GELU ~1e-3, straight-line
__device__ __forceinline__ float gelu_t(float x) {
  float z = 0.7978845608f * fmaf(0.044715f * x, x * x, x);
  float e = __expf(2.f * z);
  float th = 1.f - 2.f / (e + 1.f);
  return 0.5f * x * (1.f + th);
}

// ---------------- LayerNorm over channel dim (bf16 out) ----------------
__global__ __launch_bounds__(256) void ln_ch(const float* __restrict__ x,
                                             const float* __restrict__ w,
                                             const float* __restrict__ b,
                                             ushort_t* __restrict__ out) {
  int p = blockIdx.x * 256 + threadIdx.x;  // over B*HW
  int bi = p >> 12;
  int pos = p & (HW_ - 1);
  const float* xb = x + (size_t)bi * C_ * HW_ + pos;
  float s = 0.f, ss = 0.f;
  for (int c = 0; c < C_; c++) {
    float v = xb[(size_t)c * HW_];
    s += v;
    ss = fmaf(v, v, ss);
  }
  float mu = s * (1.f / C_);
  float var = ss * (1.f / C_) - mu * mu;
  float inv = rsqrtf(var + 1e-5f);
  ushort_t* ob = out + (size_t)bi * C_ * HW_ + pos;
  for (int c = 0; c < C_; c++) {
    ob[(size_t)c * HW_] = f2bu((xb[(size_t)c * HW_] - mu) * inv * w[c] + b[c]);
  }
}

// ---------------- weight prep: fp32 -> bf16, all six matrices ----------------
// wq,wk,wv contiguous -> merged [384][128] qkv weight.
__global__ __launch_bounds__(256) void cvt_w(const float* __restrict__ wq,
                                             const float* __restrict__ wk,
                                             const float* __restrict__ wv,
                                             const float* __restrict__ apo,
                                             const float* __restrict__ fin,
                                             const float* __restrict__ fpo,
                                             ushort_t* __restrict__ dst) {
  int id = blockIdx.x * 256 + threadIdx.x;
  const float* src;
  int off;
  if (id < 16384) { src = wq; off = id; }
  else if (id < 32768) { src = wk; off = id - 16384; }
  else if (id < 49152) { src = wv; off = id - 32768; }
  else if (id < 98304) { src = apo; off = id - 49152; }
  else if (id < 229376) { src = fin; off = id - 98304; }
  else if (id < 425984) { src = fpo; off = id - 229376; }
  else return;
  dst[id] = f2bu(src[off]);
}

// load 16-elem window rv[j] = row[cb-4+j], zero-padded outside [0,64)
__device__ __forceinline__ void loadrow_bf(const ushort_t* __restrict__ rowp,
                                           int cb, float* rv) {
#pragma unroll
  for (int b = 0; b < 4; b++) {
    int co = cb - 4 + b * 4;
    if ((unsigned)co <= 60u) {
      us4 t = *(const us4*)(rowp + co);
      rv[b * 4 + 0] = bf2f(t.x); rv[b * 4 + 1] = bf2f(t.y);
      rv[b * 4 + 2] = bf2f(t.z); rv[b * 4 + 3] = bf2f(t.w);
    } else {
      rv[b * 4 + 0] = 0.f; rv[b * 4 + 1] = 0.f;
      rv[b * 4 + 2] = 0.f; rv[b * 4 + 3] = 0.f;
    }
  }
}

// ------- conv1x1 as bf16 MFMA GEMM: Out[cout][HW] = W[cout][cin] @ In[cin][HW] -------
// Transposed LDS tile [n][k]; B-frag = one ds_read_b128 (R14-proven).
template <typename Tin, typename Tout>
__global__ __launch_bounds__(256) void conv1x1_m(const Tin* __restrict__ in,
                                                 const ushort_t* __restrict__ wtb,
                                                 const float* __restrict__ resid,
                                                 Tout* __restrict__ out,
                                                 int cin, int cout, int wstride,
                                                 int accum) {
  constexpr int ST2 = 136;  // bf16 units per n-row (128 k + 8 pad)
  __shared__ ushort_t bsh[64 * ST2];
  int tid = threadIdx.x;
  int lane = tid & 63;
  int wid = tid >> 6;
  int lrow = lane & 15;
  int lk = lane >> 4;
  int blk = blockIdx.x;
  int nb = blk & 63;
  int rest = blk >> 6;
  int mb = cout >> 6;
  int m = rest % mb;
  int bi = rest / mb;
  int n0 = nb << 6;
  int o0 = (m << 6) + wid * 16;

  f32x4 acc[4] = {{0.f, 0.f, 0.f, 0.f}, {0.f, 0.f, 0.f, 0.f},
                  {0.f, 0.f, 0.f, 0.f}, {0.f, 0.f, 0.f, 0.f}};

  int nn = tid & 63;   // staging: n within tile
  int wk4 = tid >> 6;  // staging: k-quad selector
  for (int kc = 0; kc < cin; kc += 128) {
#pragma unroll
    for (int p = 0; p < 8; p++) {
      int kb = p * 16 + wk4 * 4;
      ushort_t u[4];
#pragma unroll
      for (int j = 0; j < 4; j++) {
        const Tin* src = in + ((size_t)bi * cin + kc + kb + j) * HW_ + n0 + nn;
        if constexpr (sizeof(Tin) == 4) {
          u[j] = f2bu(*(const float*)src);
        } else {
          u[j] = *(const ushort_t*)src;
        }
      }
      us4 w4;
      w4.x = u[0]; w4.y = u[1]; w4.z = u[2]; w4.w = u[3];
      *(us4*)&bsh[nn * ST2 + kb] = w4;
    }
    __syncthreads();
#pragma unroll
    for (int ks = 0; ks < 4; ks++) {
      const ushort_t* wr = wtb + (size_t)(o0 + lrow) * wstride + kc + ks * 32 + lk * 8;
      us4 wlo = *(const us4*)wr;
      us4 whi = *(const us4*)(wr + 4);
      bf16x8 af;
      af[0] = (short)wlo.x; af[1] = (short)wlo.y;
      af[2] = (short)wlo.z; af[3] = (short)wlo.w;
      af[4] = (short)whi.x; af[5] = (short)whi.y;
      af[6] = (short)whi.z; af[7] = (short)whi.w;
#pragma unroll
      for (int s = 0; s < 4; s++) {
        bf16x8 bf_ = *(const bf16x8*)&bsh[(s * 16 + lrow) * ST2 + ks * 32 + lk * 8];
        acc[s] = __builtin_amdgcn_mfma_f32_16x16x32_bf16(af, bf_, acc[s], 0, 0, 0);
      }
    }
    __syncthreads();
  }

  const float* rp = resid ? resid + (size_t)bi * cout * HW_ : nullptr;
  Tout* op = out + (size_t)bi * cout * HW_;
#pragma unroll
  for (int s = 0; s < 4; s++) {
#pragma unroll
    for (int r = 0; r < 4; r++) {
      int o = o0 + lk * 4 + r;
      int n = n0 + s * 16 + lrow;
      size_t off = (size_t)o * HW_ + n;
      float v = acc[s][r];
      if (rp) v += rp[off];
      if (accum) v += toF(op[off]);
      storeF(&op[off], v);
    }
  }
}

// ------- depthwise conv (bf16 in/out), fused L2 sum-of-squares for q,k -------
// Reads merged qkv0 [bi][384][HW]; sel picks the 128-channel slice.
template <int K>
__global__ __launch_bounds__(256) void dwconv_d(const ushort_t* __restrict__ qkv0,
                                                const float* __restrict__ wq_,
                                                const float* __restrict__ wk_,
                                                const float* __restrict__ wv_,
                                                ushort_t* __restrict__ qd,
                                                ushort_t* __restrict__ kd,
                                                ushort_t* __restrict__ vd,
                                                float* __restrict__ sumsq_s) {
  constexpr int P = K / 2;
  __shared__ float wsh[K * K];
  __shared__ float red[4];
  int sel = blockIdx.y;
  const float* wgt = (sel == 0) ? wq_ : (sel == 1) ? wk_ : wv_;
  ushort_t* outp = (sel == 0) ? qd : (sel == 1) ? kd : vd;
  int blk = blockIdx.x;  // B*C*2
  int half = blk & 1;
  int c = (blk >> 1) & (C_ - 1);
  int bi = blk >> 8;
  int tid = threadIdx.x;

  if (tid < K * K) wsh[tid] = wgt[(size_t)c * K * K + tid];
  __syncthreads();

  int r = tid >> 3;
  int cb = (tid & 7) << 3;
  int y = half * 32 + r;
  const ushort_t* plane = qkv0 + ((size_t)bi * 384 + sel * C_ + c) * HW_;

  float a[8];
#pragma unroll
  for (int o = 0; o < 8; o++) a[o] = 0.f;
#pragma unroll
  for (int dy = 0; dy < K; dy++) {
    int gy = y + dy - P;
    if ((unsigned)gy < 64u) {
      float rv[16];
      loadrow_bf(plane + gy * 64, cb, rv);
#pragma unroll
      for (int dx = 0; dx < K; dx++) {
        float wv = wsh[dy * K + dx];
#pragma unroll
        for (int o = 0; o < 8; o++) a[o] = fmaf(rv[o + dx + 4 - P], wv, a[o]);
      }
    }
  }
  ushort_t* ob = outp + (size_t)(bi * C_ + c) * HW_ + y * 64 + cb;
  us4 t0, t1;
  t0.x = f2bu(a[0]); t0.y = f2bu(a[1]); t0.z = f2bu(a[2]); t0.w = f2bu(a[3]);
  t1.x = f2bu(a[4]); t1.y = f2bu(a[5]); t1.z = f2bu(a[6]); t1.w = f2bu(a[7]);
  *(us4*)ob = t0;
  *(us4*)(ob + 4) = t1;

  float ssq = 0.f;
#pragma unroll
  for (int o = 0; o < 8; o++) ssq = fmaf(a[o], a[o], ssq);
#pragma unroll
  for (int off = 32; off >= 1; off >>= 1) ssq += __shfl_xor(ssq, off, 64);
  if ((tid & 63) == 0) red[tid >> 6] = ssq;
  __syncthreads();
  if (tid == 0 && sel < 2) {
    atomicAdd(&sumsq_s[sel * 1024 + bi * C_ + c], red[0] + red[1] + red[2] + red[3]);
  }
}

// ------- FFN depthwise conv + GEGLU gate, 2x8 patch/thread, tanh-gelu -------
template <int K>
__global__ __launch_bounds__(256) void ffn_dwgate_p(const ushort_t* __restrict__ xin,
                                                    const float* __restrict__ w,
                                                    ushort_t* __restrict__ gated) {
  constexpr int P = K / 2;
  __shared__ float wsh[2 * K * K];
  int blk = blockIdx.x;  // B*512
  int i = blk & 511;
  int bi = blk >> 9;
  int tid = threadIdx.x;

  if (tid < 2 * K * K) {
    wsh[tid] = (tid < K * K) ? w[(size_t)i * K * K + tid]
                             : w[(size_t)(512 + i) * K * K + (tid - K * K)];
  }
  __syncthreads();

  int r2 = tid >> 3;          // 0..31
  int cb = (tid & 7) << 3;
  int y0 = r2 * 2;
  const ushort_t* gin = xin + (size_t)(bi * 1024 + i) * HW_;
  const ushort_t* min_ = gin + (size_t)512 * HW_;

  float ge[16];
  {
    float a0[8], a1[8];
#pragma unroll
    for (int o = 0; o < 8; o++) { a0[o] = 0.f; a1[o] = 0.f; }
#pragma unroll
    for (int rr = 0; rr <= K; rr++) {
      int gy = y0 - P + rr;
      if ((unsigned)gy < 64u) {
        float rv[16];
        loadrow_bf(gin + gy * 64, cb, rv);
        if (rr < K) {
          float wv;
#pragma unroll
          for (int dx = 0; dx < K; dx++) {
            wv = wsh[rr * K + dx];
#pragma unroll
            for (int o = 0; o < 8; o++) a0[o] = fmaf(rv[o + dx + 4 - P], wv, a0[o]);
          }
        }
        if (rr >= 1) {
          float wv;
#pragma unroll
          for (int dx = 0; dx < K; dx++) {
            wv = wsh[(rr - 1) * K + dx];
#pragma unroll
            for (int o = 0; o < 8; o++) a1[o] = fmaf(rv[o + dx + 4 - P], wv, a1[o]);
          }
        }
      }
    }
#pragma unroll
    for (int o = 0; o < 8; o++) { ge[o] = gelu_t(a0[o]); ge[8 + o] = gelu_t(a1[o]); }
  }

  float m0[8], m1[8];
#pragma unroll
  for (int o = 0; o < 8; o++) { m0[o] = 0.f; m1[o] = 0.f; }
#pragma unroll
  for (int rr = 0; rr <= K; rr++) {
    int gy = y0 - P + rr;
    if ((unsigned)gy < 64u) {
      float rv[16];
      loadrow_bf(min_ + gy * 64, cb, rv);
      if (rr < K) {
        float wv;
#pragma unroll
        for (int dx = 0; dx < K; dx++) {
          wv = wsh[K * K + rr * K + dx];
#pragma unroll
          for (int o = 0; o < 8; o++) m0[o] = fmaf(rv[o + dx + 4 - P], wv, m0[o]);
        }
      }
      if (rr >= 1) {
        float wv;
#pragma unroll
        for (int dx = 0; dx < K; dx++) {
          wv = wsh[K * K + (rr - 1) * K + dx];
#pragma unroll
          for (int o = 0; o < 8; o++) m1[o] = fmaf(rv[o + dx + 4 - P], wv, m1[o]);
        }
      }
    }
  }
  ushort_t* gp = gated + (size_t)(bi * 512 + i) * HW_ + y0 * 64 + cb;
#pragma unroll
  for (int v = 0; v < 2; v++) {
    us4 t;
    t.x = f2bu(ge[v * 4 + 0] * m0[v * 4 + 0]);
    t.y = f2bu(ge[v * 4 + 1] * m0[v * 4 + 1]);
    t.z = f2bu(ge[v * 4 + 2] * m0[v * 4 + 2]);
    t.w = f2bu(ge[v * 4 + 3] * m0[v * 4 + 3]);
    *(us4*)(gp + v * 4) = t;
  }
  gp += 64;
#pragma unroll
  for (int v = 0; v < 2; v++) {
    us4 t;
    t.x = f2bu(ge[8 + v * 4 + 0] * m1[v * 4 + 0]);
    t.y = f2bu(ge[8 + v * 4 + 1] * m1[v * 4 + 1]);
    t.z = f2bu(ge[8 + v * 4 + 2] * m1[v * 4 + 2]);
    t.w = f2bu(ge[8 + v * 4 + 3] * m1[v * 4 + 3]);
    *(us4*)(gp + v * 4) = t;
  }
}

// ---------------- attention: partial scores over 256-position chunks (bf16 in) ----------------
__global__ __launch_bounds__(256) void attn_score_part(const ushort_t* __restrict__ qd,
                                                       const ushort_t* __restrict__ kd,
                                                       float* __restrict__ part) {
  constexpr int ST = 258;
  __shared__ float qs[16 * ST];
  __shared__ float ks[16 * ST];
  int bh = blockIdx.x;   // 64
  int ch = blockIdx.y;   // 16 chunks of 256
  int bi = bh >> 3;
  int h = bh & 7;
  int tid = threadIdx.x;
  int c = tid >> 4;
  int d = tid & 15;

  const ushort_t* qrow = qd + (size_t)(bi * C_ + h * CH_) * HW_ + ch * 256;
  const ushort_t* krow = kd + (size_t)(bi * C_ + h * CH_) * HW_ + ch * 256;
#pragma unroll
  for (int it = 0; it < 4; it++) {
    int idx = tid + it * 256;
    int r = idx >> 6, q4 = idx & 63;
    us4 qv = *(const us4*)(qrow + (size_t)r * HW_ + q4 * 4);
    us4 kv = *(const us4*)(krow + (size_t)r * HW_ + q4 * 4);
    float* qdst = &qs[r * ST + q4 * 4];
    float* kdst = &ks[r * ST + q4 * 4];
    qdst[0] = bf2f(qv.x); qdst[1] = bf2f(qv.y); qdst[2] = bf2f(qv.z); qdst[3] = bf2f(qv.w);
    kdst[0] = bf2f(kv.x); kdst[1] = bf2f(kv.y); kdst[2] = bf2f(kv.z); kdst[3] = bf2f(kv.w);
  }
  __syncthreads();

  const float* qp = &qs[c * ST];
  const float* kp = &ks[d * ST];
  float acc = 0.f;
#pragma unroll 8
  for (int j = 0; j < 256; j++) acc = fmaf(qp[j], kp[j], acc);
  part[((size_t)bh * 16 + ch) * 256 + tid] = acc;
}

// ---------------- attention: reduce partials + softmax (inline inv-norms) ----------------
__global__ __launch_bounds__(256) void attn_softmax(const float* __restrict__ part,
                                                    const float* __restrict__ sumsq_s,
                                                    const float* __restrict__ temp,
                                                    float* __restrict__ as_buf) {
  int bh = blockIdx.x;  // 64
  int bi = bh >> 3;
  int h = bh & 7;
  int tid = threadIdx.x;
  int c = tid >> 4;
  int d = tid & 15;
  float s = 0.f;
  const float* pp = part + (size_t)bh * 16 * 256 + tid;
#pragma unroll
  for (int ch = 0; ch < 16; ch++) s += pp[ch * 256];
  float sq = sumsq_s[bi * C_ + h * CH_ + c];
  float sk = sumsq_s[1024 + bi * C_ + h * CH_ + d];
  float invq = 1.f / fmaxf(sqrtf(sq), 1e-12f);
  float invk = 1.f / fmaxf(sqrtf(sk), 1e-12f);
  float S = s * invq * invk * temp[h];
  float mx = S;
#pragma unroll
  for (int o = 8; o >= 1; o >>= 1) mx = fmaxf(mx, __shfl_xor(mx, o, 16));
  float e = expf(S - mx);
  float sm = e;
#pragma unroll
  for (int o = 8; o >= 1; o >>= 1) sm += __shfl_xor(sm, o, 16);
  as_buf[(size_t)bh * 256 + tid] = e / sm;
}

// ------- attention: PV; writes into merged osb_all [bi][384][HW] at scale slice -------
__global__ __launch_bounds__(256) void attn_pv(const ushort_t* __restrict__ vd,
                                               const float* __restrict__ as_buf,
                                               ushort_t* __restrict__ osb_all,
                                               int coff) {
  __shared__ float as[16][17];
  int bh = blockIdx.x;  // 64
  int ch = blockIdx.y;  // 16
  int bi = bh >> 3;
  int h = bh & 7;
  int tid = threadIdx.x;
  if (tid < 256) {
    int cc = tid >> 4, dd = tid & 15;
    as[cc][dd] = as_buf[(size_t)bh * 256 + tid];
  }
  __syncthreads();

  int n = ch * 256 + tid;
  const ushort_t* vrow = vd + (size_t)(bi * C_ + h * CH_) * HW_ + n;
  float o_[16];
#pragma unroll
  for (int cc = 0; cc < 16; cc++) o_[cc] = 0.f;
#pragma unroll
  for (int dd = 0; dd < 16; dd++) {
    float vv = bf2f(vrow[(size_t)dd * HW_]);
#pragma unroll
    for (int cc = 0; cc < 16; cc++) o_[cc] = fmaf(as[cc][dd], vv, o_[cc]);
  }
  ushort_t* ob = osb_all + ((size_t)bi * 384 + coff + h * CH_) * HW_ + n;
#pragma unroll
  for (int cc = 0; cc < 16; cc++) ob[(size_t)cc * HW_] = f2bu(o_[cc]);
}

extern "C" void kernel_launch(void* const* d_in, const int* in_sizes, int n_in,
                              void* d_out, int out_size, void* d_ws, size_t ws_size,
                              hipStream_t stream) {
  const float* x = (const float*)d_in[0];
  const float* ln1_w = (const float*)d_in[1];
  const float* ln1_b = (const float*)d_in[2];
  const float* temp = (const float*)d_in[3];
  const float* wq = (const float*)d_in[4];
  const float* wk = (const float*)d_in[5];
  const float* wv = (const float*)d_in[6];
  const float* dw[9];
  for (int i = 0; i < 9; i++) dw[i] = (const float*)d_in[7 + i];
  const float* attn_po = (const float*)d_in[16];
  const float* ln2_w = (const float*)d_in[17];
  const float* ln2_b = (const float*)d_in[18];
  const float* ffn_in = (const float*)d_in[19];
  const float* ffn_dw[3] = {(const float*)d_in[20], (const float*)d_in[21],
                            (const float*)d_in[22]};
  const float* ffn_po = (const float*)d_in[23];
  float* out = (float*)d_out;

  // ---- workspace layout (bf16 intermediates), lifetime-aliased ----
  // 0-8:   xnb (LN out, dies after qkv/ffn_in GEMM) / part (1MB, attn phase)
  // 16-40: qkv0 [bi][384][HW] (24MB)        | FFN: xin 16-80 (64MB)
  // 40-64: qdb,kdb,vdb (8MB each)           |
  // 64-88: osb_all [bi][384][HW] (24MB)     |
  // 80-112:                                  | FFN: gated (32MB)
  // 112-128: x2 fp32 residual stream
  const size_t MB = (size_t)1 << 20;
  char* wsb = (char*)d_ws;
  ushort_t* xnb = (ushort_t*)(wsb + 0 * MB);
  float* part = (float*)(wsb + 0 * MB);  // 1MB; xnb dead when used
  ushort_t* qkv0 = (ushort_t*)(wsb + 16 * MB);     // 24MB
  ushort_t* qdb = (ushort_t*)(wsb + 40 * MB);      // 8MB
  ushort_t* kdb = (ushort_t*)(wsb + 48 * MB);
  ushort_t* vdb = (ushort_t*)(wsb + 56 * MB);
  ushort_t* osb_all = (ushort_t*)(wsb + 64 * MB);  // 24MB
  float* x2 = (float*)(wsb + 112 * MB);            // 16MB
  float* as_buf = (float*)(wsb + 128 * MB);                  // 64 KiB
  float* sumsq = (float*)(wsb + 128 * MB + 64 * 1024);       // 24 KiB
  ushort_t* wbuf = (ushort_t*)(wsb + 128 * MB + 96 * 1024);  // 832 KiB
  ushort_t* xin = (ushort_t*)(wsb + 16 * MB);      // 64MB (attn buffers dead)
  ushort_t* gated = (ushort_t*)(wsb + 80 * MB);    // 32MB (clears x2@112)

  const ushort_t* wb_qkv = wbuf;            // [384][128]
  const ushort_t* wb_apo = wbuf + 49152;    // [128][384]
  const ushort_t* wb_fin = wbuf + 98304;    // [1024][128]
  const ushort_t* wb_fpo = wbuf + 229376;   // [128][1536]

  const int ln_grid = (B_ * HW_) / 256;                  // 128
  const int g_qkv = B_ * (384 / 64) * 64;                // 3072
  const int g128 = B_ * (C_ / 64) * 64;                  // 1024
  const int g1024 = B_ * (1024 / 64) * 64;               // 8192
  const dim3 dwt_grid(B_ * C_ * 2, 3);                   // 2048 x 3
  const int ffg_grid = B_ * 512;                         // 4096
  const dim3 att_grid(B_ * HEADS_, 16);                  // 64 x 16

  // ---- prep ----
  hipMemsetAsync(sumsq, 0, 3 * 2048 * sizeof(float), stream);
  cvt_w<<<1664, 256, 0, stream>>>(wq, wk, wv, attn_po, ffn_in, ffn_po, wbuf);

  // ---- attention branch ----
  ln_ch<<<ln_grid, 256, 0, stream>>>(x, ln1_w, ln1_b, xnb);
  conv1x1_m<ushort_t, ushort_t><<<g_qkv, 256, 0, stream>>>(
      xnb, wb_qkv, nullptr, qkv0, C_, 384, C_, 0);

  for (int s = 0; s < 3; s++) {
    float* sumsq_s = sumsq + s * 2048;
    if (s == 0)
      dwconv_d<3><<<dwt_grid, 256, 0, stream>>>(qkv0, dw[0], dw[1], dw[2],
                                                qdb, kdb, vdb, sumsq_s);
    else if (s == 1)
      dwconv_d<5><<<dwt_grid, 256, 0, stream>>>(qkv0, dw[3], dw[4], dw[5],
                                                qdb, kdb, vdb, sumsq_s);
    else
      dwconv_d<7><<<dwt_grid, 256, 0, stream>>>(qkv0, dw[6], dw[7], dw[8],
                                                qdb, kdb, vdb, sumsq_s);
    attn_score_part<<<att_grid, 256, 0, stream>>>(qdb, kdb, part);
    attn_softmax<<<B_ * HEADS_, 256, 0, stream>>>(part, sumsq_s, temp, as_buf);
    attn_pv<<<att_grid, 256, 0, stream>>>(vdb, as_buf, osb_all, s * C_);
  }
  // single merged attn_po GEMM: x2 = x + attn_po @ osb_all (cin=384)
  conv1x1_m<ushort_t, float><<<g128, 256, 0, stream>>>(
      osb_all, wb_apo, x, x2, 384, C_, 384, 0);

  // ---- FFN branch ----
  ln_ch<<<ln_grid, 256, 0, stream>>>(x2, ln2_w, ln2_b, xnb);
  conv1x1_m<ushort_t, ushort_t><<<g1024, 256, 0, stream>>>(
      xnb, wb_fin, nullptr, xin, C_, 1024, C_, 0);

  for (int s = 0; s < 3; s++) {
    if (s == 0)
      ffn_dwgate_p<3><<<ffg_grid, 256, 0, stream>>>(xin, ffn_dw[0], gated);
    else if (s == 1)
      ffn_dwgate_p<5><<<ffg_grid, 256, 0, stream>>>(xin, ffn_dw[1], gated);
    else
      ffn_dwgate_p<7><<<ffg_grid, 256, 0, stream>>>(xin, ffn_dw[2], gated);
    conv1x1_m<ushort_t, float><<<g128, 256, 0, stream>>>(
        gated, wb_fpo + s * 512, (s == 0) ? x2 : nullptr, out, 512, C_, 3 * HID_,
        s == 0 ? 0 : 1);
  }
  (void)in_sizes; (void)n_in; (void)out_size; (void)ws_size;
}

// Round 17
// 441.478 us; speedup vs baseline: 1.2387x; 1.0004x over previous
//
#include <hip/hip_runtime.h>
#include <hip/hip_bf16.h>
#include <math.h>

#define B_ 8
#define C_ 128
#define H_ 64
#define W_ 64
#define HW_ 4096
#define HEADS_ 8
#define CH_ 16
#define HID_ 512

typedef unsigned short ushort_t;
struct __attribute__((aligned(8))) us4 { ushort_t x, y, z, w; };

typedef __attribute__((ext_vector_type(8))) short bf16x8;
typedef __attribute__((ext_vector_type(4))) float f32x4;

__device__ __forceinline__ float bf2f(ushort_t u) {
  return __uint_as_float(((unsigned int)u) << 16);
}
__device__ __forceinline__ ushort_t f2bu(float f) {
  __hip_bfloat16 h = __float2bfloat16(f);
  return *reinterpret_cast<ushort_t*>(&h);
}
__device__ __forceinline__ float toF(float v) { return v; }
__device__ __forceinline__ float toF(ushort_t v) { return bf2f(v); }
__device__ __forceinline__ void storeF(float* p, float v) { *p = v; }
__device__ __forceinline__ void storeF(ushort_t* p, float v) { *p = f2bu(v); }

// tanh-GELU: max dev from exact erf-GELU ~1e-3, straight-line
__device__ __forceinline__ float gelu_t(float x) {
  float z = 0.7978845608f * fmaf(0.044715f * x, x * x, x);
  float e = __expf(2.f * z);
  float th = 1.f - 2.f / (e + 1.f);
  return 0.5f * x * (1.f + th);
}

// ---------------- LayerNorm over channel dim (bf16 out) ----------------
__global__ __launch_bounds__(256) void ln_ch(const float* __restrict__ x,
                                             const float* __restrict__ w,
                                             const float* __restrict__ b,
                                             ushort_t* __restrict__ out) {
  int p = blockIdx.x * 256 + threadIdx.x;  // over B*HW
  int bi = p >> 12;
  int pos = p & (HW_ - 1);
  const float* xb = x + (size_t)bi * C_ * HW_ + pos;
  float s = 0.f, ss = 0.f;
  for (int c = 0; c < C_; c++) {
    float v = xb[(size_t)c * HW_];
    s += v;
    ss = fmaf(v, v, ss);
  }
  float mu = s * (1.f / C_);
  float var = ss * (1.f / C_) - mu * mu;
  float inv = rsqrtf(var + 1e-5f);
  ushort_t* ob = out + (size_t)bi * C_ * HW_ + pos;
  for (int c = 0; c < C_; c++) {
    ob[(size_t)c * HW_] = f2bu((xb[(size_t)c * HW_] - mu) * inv * w[c] + b[c]);
  }
}

// ---------------- weight prep: fp32 -> bf16, all six matrices ----------------
__global__ __launch_bounds__(256) void cvt_w(const float* __restrict__ wq,
                                             const float* __restrict__ wk,
                                             const float* __restrict__ wv,
                                             const float* __restrict__ apo,
                                             const float* __restrict__ fin,
                                             const float* __restrict__ fpo,
                                             ushort_t* __restrict__ dst) {
  int id = blockIdx.x * 256 + threadIdx.x;
  const float* src;
  int off;
  if (id < 16384) { src = wq; off = id; }
  else if (id < 32768) { src = wk; off = id - 16384; }
  else if (id < 49152) { src = wv; off = id - 32768; }
  else if (id < 98304) { src = apo; off = id - 49152; }
  else if (id < 229376) { src = fin; off = id - 98304; }
  else if (id < 425984) { src = fpo; off = id - 229376; }
  else return;
  dst[id] = f2bu(src[off]);
}

// load 16-elem window rv[j] = row[cb-4+j], zero-padded outside [0,64)
__device__ __forceinline__ void loadrow_bf(const ushort_t* __restrict__ rowp,
                                           int cb, float* rv) {
#pragma unroll
  for (int b = 0; b < 4; b++) {
    int co = cb - 4 + b * 4;
    if ((unsigned)co <= 60u) {
      us4 t = *(const us4*)(rowp + co);
      rv[b * 4 + 0] = bf2f(t.x); rv[b * 4 + 1] = bf2f(t.y);
      rv[b * 4 + 2] = bf2f(t.z); rv[b * 4 + 3] = bf2f(t.w);
    } else {
      rv[b * 4 + 0] = 0.f; rv[b * 4 + 1] = 0.f;
      rv[b * 4 + 2] = 0.f; rv[b * 4 + 3] = 0.f;
    }
  }
}

// ------- conv1x1 as bf16 MFMA GEMM: Out[cout][HW] = W[cout][cin] @ In[cin][HW] -------
template <typename Tin, typename Tout>
__global__ __launch_bounds__(256) void conv1x1_m(const Tin* __restrict__ in,
                                                 const ushort_t* __restrict__ wtb,
                                                 const float* __restrict__ resid,
                                                 Tout* __restrict__ out,
                                                 int cin, int cout, int wstride,
                                                 int accum) {
  constexpr int ST2 = 136;
  __shared__ ushort_t bsh[64 * ST2];
  int tid = threadIdx.x;
  int lane = tid & 63;
  int wid = tid >> 6;
  int lrow = lane & 15;
  int lk = lane >> 4;
  int blk = blockIdx.x;
  int nb = blk & 63;
  int rest = blk >> 6;
  int mb = cout >> 6;
  int m = rest % mb;
  int bi = rest / mb;
  int n0 = nb << 6;
  int o0 = (m << 6) + wid * 16;

  f32x4 acc[4] = {{0.f, 0.f, 0.f, 0.f}, {0.f, 0.f, 0.f, 0.f},
                  {0.f, 0.f, 0.f, 0.f}, {0.f, 0.f, 0.f, 0.f}};

  int nn = tid & 63;
  int wk4 = tid >> 6;
  for (int kc = 0; kc < cin; kc += 128) {
#pragma unroll
    for (int p = 0; p < 8; p++) {
      int kb = p * 16 + wk4 * 4;
      ushort_t u[4];
#pragma unroll
      for (int j = 0; j < 4; j++) {
        const Tin* src = in + ((size_t)bi * cin + kc + kb + j) * HW_ + n0 + nn;
        if constexpr (sizeof(Tin) == 4) {
          u[j] = f2bu(*(const float*)src);
        } else {
          u[j] = *(const ushort_t*)src;
        }
      }
      us4 w4;
      w4.x = u[0]; w4.y = u[1]; w4.z = u[2]; w4.w = u[3];
      *(us4*)&bsh[nn * ST2 + kb] = w4;
    }
    __syncthreads();
#pragma unroll
    for (int ks = 0; ks < 4; ks++) {
      const ushort_t* wr = wtb + (size_t)(o0 + lrow) * wstride + kc + ks * 32 + lk * 8;
      us4 wlo = *(const us4*)wr;
      us4 whi = *(const us4*)(wr + 4);
      bf16x8 af;
      af[0] = (short)wlo.x; af[1] = (short)wlo.y;
      af[2] = (short)wlo.z; af[3] = (short)wlo.w;
      af[4] = (short)whi.x; af[5] = (short)whi.y;
      af[6] = (short)whi.z; af[7] = (short)whi.w;
#pragma unroll
      for (int s = 0; s < 4; s++) {
        bf16x8 bf_ = *(const bf16x8*)&bsh[(s * 16 + lrow) * ST2 + ks * 32 + lk * 8];
        acc[s] = __builtin_amdgcn_mfma_f32_16x16x32_bf16(af, bf_, acc[s], 0, 0, 0);
      }
    }
    __syncthreads();
  }

  const float* rp = resid ? resid + (size_t)bi * cout * HW_ : nullptr;
  Tout* op = out + (size_t)bi * cout * HW_;
#pragma unroll
  for (int s = 0; s < 4; s++) {
#pragma unroll
    for (int r = 0; r < 4; r++) {
      int o = o0 + lk * 4 + r;
      int n = n0 + s * 16 + lrow;
      size_t off = (size_t)o * HW_ + n;
      float v = acc[s][r];
      if (rp) v += rp[off];
      if (accum) v += toF(op[off]);
      storeF(&op[off], v);
    }
  }
}

// ------- depthwise conv (bf16 in/out), fused L2 sum-of-squares for q,k -------
template <int K>
__global__ __launch_bounds__(256) void dwconv_d(const ushort_t* __restrict__ qkv0,
                                                const float* __restrict__ wq_,
                                                const float* __restrict__ wk_,
                                                const float* __restrict__ wv_,
                                                ushort_t* __restrict__ qd,
                                                ushort_t* __restrict__ kd,
                                                ushort_t* __restrict__ vd,
                                                float* __restrict__ sumsq_s) {
  constexpr int P = K / 2;
  __shared__ float wsh[K * K];
  __shared__ float red[4];
  int sel = blockIdx.y;
  const float* wgt = (sel == 0) ? wq_ : (sel == 1) ? wk_ : wv_;
  ushort_t* outp = (sel == 0) ? qd : (sel == 1) ? kd : vd;
  int blk = blockIdx.x;  // B*C*2
  int half = blk & 1;
  int c = (blk >> 1) & (C_ - 1);
  int bi = blk >> 8;
  int tid = threadIdx.x;

  if (tid < K * K) wsh[tid] = wgt[(size_t)c * K * K + tid];
  __syncthreads();

  int r = tid >> 3;
  int cb = (tid & 7) << 3;
  int y = half * 32 + r;
  const ushort_t* plane = qkv0 + ((size_t)bi * 384 + sel * C_ + c) * HW_;

  float a[8];
#pragma unroll
  for (int o = 0; o < 8; o++) a[o] = 0.f;
#pragma unroll
  for (int dy = 0; dy < K; dy++) {
    int gy = y + dy - P;
    if ((unsigned)gy < 64u) {
      float rv[16];
      loadrow_bf(plane + gy * 64, cb, rv);
#pragma unroll
      for (int dx = 0; dx < K; dx++) {
        float wv = wsh[dy * K + dx];
#pragma unroll
        for (int o = 0; o < 8; o++) a[o] = fmaf(rv[o + dx + 4 - P], wv, a[o]);
      }
    }
  }
  ushort_t* ob = outp + (size_t)(bi * C_ + c) * HW_ + y * 64 + cb;
  us4 t0, t1;
  t0.x = f2bu(a[0]); t0.y = f2bu(a[1]); t0.z = f2bu(a[2]); t0.w = f2bu(a[3]);
  t1.x = f2bu(a[4]); t1.y = f2bu(a[5]); t1.z = f2bu(a[6]); t1.w = f2bu(a[7]);
  *(us4*)ob = t0;
  *(us4*)(ob + 4) = t1;

  float ssq = 0.f;
#pragma unroll
  for (int o = 0; o < 8; o++) ssq = fmaf(a[o], a[o], ssq);
#pragma unroll
  for (int off = 32; off >= 1; off >>= 1) ssq += __shfl_xor(ssq, off, 64);
  if ((tid & 63) == 0) red[tid >> 6] = ssq;
  __syncthreads();
  if (tid == 0 && sel < 2) {
    atomicAdd(&sumsq_s[sel * 1024 + bi * C_ + c], red[0] + red[1] + red[2] + red[3]);
  }
}

// ------- FFN depthwise conv + GEGLU gate, 4x8 patch/thread, 128-thr blocks -------
// K+3 row loads serve 4 output rows (vs K+1 per 2 rows): ~37% fewer loads/cvt at K=7.
template <int K>
__global__ __launch_bounds__(128) void ffn_dwgate_p(const ushort_t* __restrict__ xin,
                                                    const float* __restrict__ w,
                                                    ushort_t* __restrict__ gated) {
  constexpr int P = K / 2;
  __shared__ float wsh[2 * K * K];
  int blk = blockIdx.x;  // B*512
  int i = blk & 511;
  int bi = blk >> 9;
  int tid = threadIdx.x;  // 0..127

  if (tid < 2 * K * K) {
    wsh[tid] = (tid < K * K) ? w[(size_t)i * K * K + tid]
                             : w[(size_t)(512 + i) * K * K + (tid - K * K)];
  }
  __syncthreads();

  int rg = tid >> 3;          // 0..15
  int cb = (tid & 7) << 3;
  int y0 = rg * 4;            // rows y0..y0+3
  const ushort_t* gin = xin + (size_t)(bi * 1024 + i) * HW_;
  const ushort_t* min_ = gin + (size_t)512 * HW_;

  float ge[4][8];
  {
    float a[4][8];
#pragma unroll
    for (int j = 0; j < 4; j++)
#pragma unroll
      for (int o = 0; o < 8; o++) a[j][o] = 0.f;
#pragma unroll
    for (int rr = 0; rr < K + 3; rr++) {
      int gy = y0 - P + rr;
      if ((unsigned)gy < 64u) {
        float rv[16];
        loadrow_bf(gin + gy * 64, cb, rv);
#pragma unroll
        for (int j = 0; j < 4; j++) {
          constexpr int dummy = 0; (void)dummy;
          int dy = rr - j;
          if (dy >= 0 && dy < K) {
#pragma unroll
            for (int dx = 0; dx < K; dx++) {
              float wv = wsh[dy * K + dx];
#pragma unroll
              for (int o = 0; o < 8; o++) a[j][o] = fmaf(rv[o + dx + 4 - P], wv, a[j][o]);
            }
          }
        }
      }
    }
#pragma unroll
    for (int j = 0; j < 4; j++)
#pragma unroll
      for (int o = 0; o < 8; o++) ge[j][o] = gelu_t(a[j][o]);
  }

  float ma[4][8];
#pragma unroll
  for (int j = 0; j < 4; j++)
#pragma unroll
    for (int o = 0; o < 8; o++) ma[j][o] = 0.f;
#pragma unroll
  for (int rr = 0; rr < K + 3; rr++) {
    int gy = y0 - P + rr;
    if ((unsigned)gy < 64u) {
      float rv[16];
      loadrow_bf(min_ + gy * 64, cb, rv);
#pragma unroll
      for (int j = 0; j < 4; j++) {
        int dy = rr - j;
        if (dy >= 0 && dy < K) {
#pragma unroll
          for (int dx = 0; dx < K; dx++) {
            float wv = wsh[K * K + dy * K + dx];
#pragma unroll
            for (int o = 0; o < 8; o++) ma[j][o] = fmaf(rv[o + dx + 4 - P], wv, ma[j][o]);
          }
        }
      }
    }
  }
  ushort_t* gp = gated + (size_t)(bi * 512 + i) * HW_ + y0 * 64 + cb;
#pragma unroll
  for (int j = 0; j < 4; j++) {
#pragma unroll
    for (int v = 0; v < 2; v++) {
      us4 t;
      t.x = f2bu(ge[j][v * 4 + 0] * ma[j][v * 4 + 0]);
      t.y = f2bu(ge[j][v * 4 + 1] * ma[j][v * 4 + 1]);
      t.z = f2bu(ge[j][v * 4 + 2] * ma[j][v * 4 + 2]);
      t.w = f2bu(ge[j][v * 4 + 3] * ma[j][v * 4 + 3]);
      *(us4*)(gp + j * 64 + v * 4) = t;
    }
  }
}

// ---------------- attention: partial scores over 256-position chunks (bf16 in) ----------------
__global__ __launch_bounds__(256) void attn_score_part(const ushort_t* __restrict__ qd,
                                                       const ushort_t* __restrict__ kd,
                                                       float* __restrict__ part) {
  constexpr int ST = 258;
  __shared__ float qs[16 * ST];
  __shared__ float ks[16 * ST];
  int bh = blockIdx.x;   // 64
  int ch = blockIdx.y;   // 16 chunks of 256
  int bi = bh >> 3;
  int h = bh & 7;
  int tid = threadIdx.x;
  int c = tid >> 4;
  int d = tid & 15;

  const ushort_t* qrow = qd + (size_t)(bi * C_ + h * CH_) * HW_ + ch * 256;
  const ushort_t* krow = kd + (size_t)(bi * C_ + h * CH_) * HW_ + ch * 256;
#pragma unroll
  for (int it = 0; it < 4; it++) {
    int idx = tid + it * 256;
    int r = idx >> 6, q4 = idx & 63;
    us4 qv = *(const us4*)(qrow + (size_t)r * HW_ + q4 * 4);
    us4 kv = *(const us4*)(krow + (size_t)r * HW_ + q4 * 4);
    float* qdst = &qs[r * ST + q4 * 4];
    float* kdst = &ks[r * ST + q4 * 4];
    qdst[0] = bf2f(qv.x); qdst[1] = bf2f(qv.y); qdst[2] = bf2f(qv.z); qdst[3] = bf2f(qv.w);
    kdst[0] = bf2f(kv.x); kdst[1] = bf2f(kv.y); kdst[2] = bf2f(kv.z); kdst[3] = bf2f(kv.w);
  }
  __syncthreads();

  const float* qp = &qs[c * ST];
  const float* kp = &ks[d * ST];
  float acc = 0.f;
#pragma unroll 8
  for (int j = 0; j < 256; j++) acc = fmaf(qp[j], kp[j], acc);
  part[((size_t)bh * 16 + ch) * 256 + tid] = acc;
}

// ------- attention: fused softmax + PV; writes merged osb_all [bi][384][HW] -------
// Each (bh, ch) block redundantly computes the 16x16 softmax from part (L2-hot).
__global__ __launch_bounds__(256) void attn_pv_sm(const ushort_t* __restrict__ vd,
                                                  const float* __restrict__ part,
                                                  const float* __restrict__ sumsq_s,
                                                  const float* __restrict__ temp,
                                                  ushort_t* __restrict__ osb_all,
                                                  int coff) {
  __shared__ float as[16][17];
  int bh = blockIdx.x;  // 64
  int ch = blockIdx.y;  // 16
  int bi = bh >> 3;
  int h = bh & 7;
  int tid = threadIdx.x;

  {
    int c = tid >> 4;
    int d = tid & 15;
    float s = 0.f;
    const float* pp = part + (size_t)bh * 16 * 256 + tid;
#pragma unroll
    for (int c2 = 0; c2 < 16; c2++) s += pp[c2 * 256];
    float sq = sumsq_s[bi * C_ + h * CH_ + c];
    float sk = sumsq_s[1024 + bi * C_ + h * CH_ + d];
    float invq = 1.f / fmaxf(sqrtf(sq), 1e-12f);
    float invk = 1.f / fmaxf(sqrtf(sk), 1e-12f);
    float S = s * invq * invk * temp[h];
    float mx = S;
#pragma unroll
    for (int o = 8; o >= 1; o >>= 1) mx = fmaxf(mx, __shfl_xor(mx, o, 16));
    float e = expf(S - mx);
    float sm = e;
#pragma unroll
    for (int o = 8; o >= 1; o >>= 1) sm += __shfl_xor(sm, o, 16);
    as[c][d] = e / sm;
  }
  __syncthreads();

  int n = ch * 256 + tid;
  const ushort_t* vrow = vd + (size_t)(bi * C_ + h * CH_) * HW_ + n;
  float o_[16];
#pragma unroll
  for (int cc = 0; cc < 16; cc++) o_[cc] = 0.f;
#pragma unroll
  for (int dd = 0; dd < 16; dd++) {
    float vv = bf2f(vrow[(size_t)dd * HW_]);
#pragma unroll
    for (int cc = 0; cc < 16; cc++) o_[cc] = fmaf(as[cc][dd], vv, o_[cc]);
  }
  ushort_t* ob = osb_all + ((size_t)bi * 384 + coff + h * CH_) * HW_ + n;
#pragma unroll
  for (int cc = 0; cc < 16; cc++) ob[(size_t)cc * HW_] = f2bu(o_[cc]);
}

extern "C" void kernel_launch(void* const* d_in, const int* in_sizes, int n_in,
                              void* d_out, int out_size, void* d_ws, size_t ws_size,
                              hipStream_t stream) {
  const float* x = (const float*)d_in[0];
  const float* ln1_w = (const float*)d_in[1];
  const float* ln1_b = (const float*)d_in[2];
  const float* temp = (const float*)d_in[3];
  const float* wq = (const float*)d_in[4];
  const float* wk = (const float*)d_in[5];
  const float* wv = (const float*)d_in[6];
  const float* dw[9];
  for (int i = 0; i < 9; i++) dw[i] = (const float*)d_in[7 + i];
  const float* attn_po = (const float*)d_in[16];
  const float* ln2_w = (const float*)d_in[17];
  const float* ln2_b = (const float*)d_in[18];
  const float* ffn_in = (const float*)d_in[19];
  const float* ffn_dw[3] = {(const float*)d_in[20], (const float*)d_in[21],
                            (const float*)d_in[22]};
  const float* ffn_po = (const float*)d_in[23];
  float* out = (float*)d_out;

  // ---- workspace layout (bf16 intermediates), lifetime-aliased ----
  const size_t MB = (size_t)1 << 20;
  char* wsb = (char*)d_ws;
  ushort_t* xnb = (ushort_t*)(wsb + 0 * MB);
  float* part = (float*)(wsb + 0 * MB);  // 1MB; xnb dead when used
  ushort_t* qkv0 = (ushort_t*)(wsb + 16 * MB);     // 24MB
  ushort_t* qdb = (ushort_t*)(wsb + 40 * MB);      // 8MB
  ushort_t* kdb = (ushort_t*)(wsb + 48 * MB);
  ushort_t* vdb = (ushort_t*)(wsb + 56 * MB);
  ushort_t* osb_all = (ushort_t*)(wsb + 64 * MB);  // 24MB
  float* x2 = (float*)(wsb + 112 * MB);            // 16MB
  float* sumsq = (float*)(wsb + 128 * MB);                   // 24 KiB
  ushort_t* wbuf = (ushort_t*)(wsb + 128 * MB + 32 * 1024);  // 832 KiB
  ushort_t* xin = (ushort_t*)(wsb + 16 * MB);      // 64MB (attn buffers dead)
  ushort_t* gated = (ushort_t*)(wsb + 80 * MB);    // 32MB

  const ushort_t* wb_qkv = wbuf;            // [384][128]
  const ushort_t* wb_apo = wbuf + 49152;    // [128][384]
  const ushort_t* wb_fin = wbuf + 98304;    // [1024][128]
  const ushort_t* wb_fpo = wbuf + 229376;   // [128][1536]

  const int ln_grid = (B_ * HW_) / 256;                  // 128
  const int g_qkv = B_ * (384 / 64) * 64;                // 3072
  const int g128 = B_ * (C_ / 64) * 64;                  // 1024
  const int g1024 = B_ * (1024 / 64) * 64;               // 8192
  const dim3 dwt_grid(B_ * C_ * 2, 3);                   // 2048 x 3
  const int ffg_grid = B_ * 512;                         // 4096
  const dim3 att_grid(B_ * HEADS_, 16);                  // 64 x 16

  // ---- prep ----
  hipMemsetAsync(sumsq, 0, 3 * 2048 * sizeof(float), stream);
  cvt_w<<<1664, 256, 0, stream>>>(wq, wk, wv, attn_po, ffn_in, ffn_po, wbuf);

  // ---- attention branch ----
  ln_ch<<<ln_grid, 256, 0, stream>>>(x, ln1_w, ln1_b, xnb);
  conv1x1_m<ushort_t, ushort_t><<<g_qkv, 256, 0, stream>>>(
      xnb, wb_qkv, nullptr, qkv0, C_, 384, C_, 0);

  for (int s = 0; s < 3; s++) {
    float* sumsq_s = sumsq + s * 2048;
    if (s == 0)
      dwconv_d<3><<<dwt_grid, 256, 0, stream>>>(qkv0, dw[0], dw[1], dw[2],
                                                qdb, kdb, vdb, sumsq_s);
    else if (s == 1)
      dwconv_d<5><<<dwt_grid, 256, 0, stream>>>(qkv0, dw[3], dw[4], dw[5],
                                                qdb, kdb, vdb, sumsq_s);
    else
      dwconv_d<7><<<dwt_grid, 256, 0, stream>>>(qkv0, dw[6], dw[7], dw[8],
                                                qdb, kdb, vdb, sumsq_s);
    attn_score_part<<<att_grid, 256, 0, stream>>>(qdb, kdb, part);
    attn_pv_sm<<<att_grid, 256, 0, stream>>>(vdb, part, sumsq_s, temp, osb_all,
                                             s * C_);
  }
  // single merged attn_po GEMM: x2 = x + attn_po @ osb_all (cin=384)
  conv1x1_m<ushort_t, float><<<g128, 256, 0, stream>>>(
      osb_all, wb_apo, x, x2, 384, C_, 384, 0);

  // ---- FFN branch ----
  ln_ch<<<ln_grid, 256, 0, stream>>>(x2, ln2_w, ln2_b, xnb);
  conv1x1_m<ushort_t, ushort_t><<<g1024, 256, 0, stream>>>(
      xnb, wb_fin, nullptr, xin, C_, 1024, C_, 0);

  for (int s = 0; s < 3; s++) {
    if (s == 0)
      ffn_dwgate_p<3><<<ffg_grid, 128, 0, stream>>>(xin, ffn_dw[0], gated);
    else if (s == 1)
      ffn_dwgate_p<5><<<ffg_grid, 128, 0, stream>>>(xin, ffn_dw[1], gated);
    else
      ffn_dwgate_p<7><<<ffg_grid, 128, 0, stream>>>(xin, ffn_dw[2], gated);
    conv1x1_m<ushort_t, float><<<g128, 256, 0, stream>>>(
        gated, wb_fpo + s * 512, (s == 0) ? x2 : nullptr, out, 512, C_, 3 * HID_,
        s == 0 ? 0 : 1);
  }
  (void)in_sizes; (void)n_in; (void)out_size; (void)ws_size;
}